// Round 1
// baseline (6358.467 us; speedup 1.0000x reference)
//
#include <hip/hip_runtime.h>

#define N_NODES 100000
#define N_EDGES 1600000
#define HIDDEN  128
#define N_CLASS 26

// ---------------- degree / norm ----------------

__global__ void deg_kernel(const int* __restrict__ col, const float* __restrict__ ew,
                           float* __restrict__ deg, int E) {
    int e = blockIdx.x * blockDim.x + threadIdx.x;
    if (e < E) atomicAdd(&deg[col[e]], ew[e]);
}

// deg includes +1.0 self-loop weight; deg >= 1 so rsqrt is safe.
__global__ void dinv_kernel(float* __restrict__ deg, int n) {
    int i = blockIdx.x * blockDim.x + threadIdx.x;
    if (i < n) deg[i] = rsqrtf(deg[i] + 1.0f);
}

__global__ void norm_kernel(const int* __restrict__ row, const int* __restrict__ col,
                            const float* __restrict__ ew, const float* __restrict__ dinv,
                            float* __restrict__ norm, int E, int n) {
    int e = blockIdx.x * blockDim.x + threadIdx.x;
    if (e < E) {
        norm[e] = dinv[row[e]] * ew[e] * dinv[col[e]];
    } else if (e < E + n) {
        int i = e - E;
        norm[e] = dinv[i] * dinv[i];
    }
}

// ---------------- GEMM1: h = x @ W1   [N,26] x [26,128] ----------------
// 16 nodes per block, 128 threads (thread j = output feature).

__global__ void gemm1_kernel(const float* __restrict__ x, const float* __restrict__ W1,
                             float* __restrict__ h) {
    __shared__ float xs[16][N_CLASS];
    const int j  = threadIdx.x;
    const int nb = blockIdx.x * 16;
    for (int t = j; t < 16 * N_CLASS; t += 128) {
        int n = t / N_CLASS, k = t % N_CLASS;
        int node = nb + n;
        xs[n][k] = (node < N_NODES) ? x[node * N_CLASS + k] : 0.0f;
    }
    __syncthreads();
    float acc[16];
#pragma unroll
    for (int n = 0; n < 16; ++n) acc[n] = 0.0f;
#pragma unroll
    for (int k = 0; k < N_CLASS; ++k) {
        float w = W1[k * HIDDEN + j];
#pragma unroll
        for (int n = 0; n < 16; ++n) acc[n] += xs[n][k] * w;
    }
#pragma unroll
    for (int n = 0; n < 16; ++n) {
        int node = nb + n;
        if (node < N_NODES) h[(size_t)node * HIDDEN + j] = acc[n];
    }
}

// ---------------- scatter: out[col] += h[row] * norm ----------------
// 32 lanes per edge, float4 gather + 4 atomic adds.

__global__ void scatter_kernel(const float* __restrict__ h, const float* __restrict__ norm,
                               const int* __restrict__ row, const int* __restrict__ col,
                               float* __restrict__ out, int E, int n) {
    long long gid = (long long)blockIdx.x * blockDim.x + threadIdx.x;
    int e = (int)(gid >> 5);
    int f = ((int)gid & 31) * 4;
    if (e >= E + n) return;
    int src, dst;
    if (e < E) { src = row[e]; dst = col[e]; }
    else       { src = dst = e - E; }
    float w = norm[e];
    float4 v = *reinterpret_cast<const float4*>(&h[(size_t)src * HIDDEN + f]);
    float* o = &out[(size_t)dst * HIDDEN + f];
    atomicAdd(o + 0, v.x * w);
    atomicAdd(o + 1, v.y * w);
    atomicAdd(o + 2, v.z * w);
    atomicAdd(o + 3, v.w * w);
}

// ---------------- GEMM2: out = relu(xin + b) @ W   [N,128] x [128,128] ----------------
// Bias + ReLU of the *previous* layer fused into the load. 16 nodes/block.

__global__ void gemm2_kernel(const float* __restrict__ xin, const float* __restrict__ b,
                             const float* __restrict__ W, float* __restrict__ out) {
    __shared__ float xs[16][HIDDEN];
    const int j  = threadIdx.x;
    const int nb = blockIdx.x * 16;
    for (int t = j; t < 16 * HIDDEN; t += 128) {
        int n = t >> 7, k = t & 127;
        int node = nb + n;
        xs[n][k] = (node < N_NODES) ? fmaxf(xin[(size_t)node * HIDDEN + k] + b[k], 0.0f) : 0.0f;
    }
    __syncthreads();
    float acc[16];
#pragma unroll
    for (int n = 0; n < 16; ++n) acc[n] = 0.0f;
    for (int k = 0; k < HIDDEN; ++k) {
        float w = W[k * HIDDEN + j];
#pragma unroll
        for (int n = 0; n < 16; ++n) acc[n] += xs[n][k] * w;
    }
#pragma unroll
    for (int n = 0; n < 16; ++n) {
        int node = nb + n;
        if (node < N_NODES) out[(size_t)node * HIDDEN + j] = acc[n];
    }
}

// ---------------- FC: out = relu(xin + b2) @ Wfc + bfc   [N,128] x [128,26] ----------------
// 8 nodes per block of 256 threads; group of 32 lanes per node, lanes 0..25 active.

__global__ void fc_kernel(const float* __restrict__ xin, const float* __restrict__ b2,
                          const float* __restrict__ Wfc, const float* __restrict__ bfc,
                          float* __restrict__ out) {
    __shared__ float xs[8][HIDDEN];
    __shared__ float wf[HIDDEN * N_CLASS];
    const int tid = threadIdx.x;
    const int nb  = blockIdx.x * 8;
    for (int t = tid; t < HIDDEN * N_CLASS; t += 256) wf[t] = Wfc[t];
    for (int t = tid; t < 8 * HIDDEN; t += 256) {
        int n = t >> 7, k = t & 127;
        int node = nb + n;
        xs[n][k] = (node < N_NODES) ? fmaxf(xin[(size_t)node * HIDDEN + k] + b2[k], 0.0f) : 0.0f;
    }
    __syncthreads();
    const int g = tid >> 5;
    const int j = tid & 31;
    const int node = nb + g;
    if (j < N_CLASS && node < N_NODES) {
        float acc = bfc[j];
#pragma unroll 8
        for (int k = 0; k < HIDDEN; ++k) acc += xs[g][k] * wf[k * N_CLASS + j];
        out[(size_t)node * N_CLASS + j] = acc;
    }
}

// ---------------- launch ----------------

extern "C" void kernel_launch(void* const* d_in, const int* in_sizes, int n_in,
                              void* d_out, int out_size, void* d_ws, size_t ws_size,
                              hipStream_t stream) {
    const float* x   = (const float*)d_in[0];
    const int*   ei  = (const int*)  d_in[1];
    const float* ew  = (const float*)d_in[2];
    const float* W1  = (const float*)d_in[3];
    const float* b1  = (const float*)d_in[4];
    const float* W2  = (const float*)d_in[5];
    const float* b2  = (const float*)d_in[6];
    const float* Wfc = (const float*)d_in[7];
    const float* bfc = (const float*)d_in[8];
    float* out = (float*)d_out;

    const int n = N_NODES, E = N_EDGES;
    const int* row = ei;        // edge_index[0]
    const int* col = ei + E;    // edge_index[1]

    char* ws = (char*)d_ws;
    size_t off = 0;
    auto alloc = [&](size_t bytes) -> void* {
        void* p = ws + off;
        off += (bytes + 255) & ~(size_t)255;
        return p;
    };
    float* dinv = (float*)alloc((size_t)n * 4);
    float* norm = (float*)alloc((size_t)(E + n) * 4);
    float* A    = (float*)alloc((size_t)n * HIDDEN * 4);   // h1, later h2
    float* B    = (float*)alloc((size_t)n * HIDDEN * 4);   // agg1, later agg2

    // deg -> dinv -> norm
    hipMemsetAsync(dinv, 0, (size_t)n * 4, stream);
    deg_kernel<<<(E + 255) / 256, 256, 0, stream>>>(col, ew, dinv, E);
    dinv_kernel<<<(n + 255) / 256, 256, 0, stream>>>(dinv, n);
    norm_kernel<<<(E + n + 255) / 256, 256, 0, stream>>>(row, col, ew, dinv, norm, E, n);

    // layer 1
    gemm1_kernel<<<(n + 15) / 16, 128, 0, stream>>>(x, W1, A);
    hipMemsetAsync(B, 0, (size_t)n * HIDDEN * 4, stream);
    {
        long long threads = (long long)(E + n) * 32;
        scatter_kernel<<<(unsigned)((threads + 255) / 256), 256, 0, stream>>>(A, norm, row, col, B, E, n);
    }

    // layer 2 (reads B with bias1+relu fused, writes A)
    gemm2_kernel<<<(n + 15) / 16, 128, 0, stream>>>(B, b1, W2, A);
    hipMemsetAsync(B, 0, (size_t)n * HIDDEN * 4, stream);
    {
        long long threads = (long long)(E + n) * 32;
        scatter_kernel<<<(unsigned)((threads + 255) / 256), 256, 0, stream>>>(A, norm, row, col, B, E, n);
    }

    // final FC (reads B with bias2+relu fused)
    fc_kernel<<<(n + 7) / 8, 256, 0, stream>>>(B, b2, Wfc, bfc, out);
}

// Round 2
// 1089.240 us; speedup vs baseline: 5.8375x; 5.8375x over previous
//
#include <hip/hip_runtime.h>

#define N_NODES 100000
#define N_EDGES 1600000
#define HIDDEN  128
#define N_CLASS 26
#define SCAN_B  256
#define NB ((N_NODES + SCAN_B - 1) / SCAN_B)   // 391 blocks

// ---------------- degree (float) + histogram (int) ----------------

__global__ void deg_hist_kernel(const int* __restrict__ col, const float* __restrict__ ew,
                                float* __restrict__ deg, int* __restrict__ cnt, int E) {
    int e = blockIdx.x * blockDim.x + threadIdx.x;
    if (e < E) {
        int c = col[e];
        atomicAdd(&deg[c], ew[e]);
        atomicAdd(&cnt[c], 1);
    }
}

// deg excludes the self-loop weight; add 1.0 here. deg+1 >= 1 so rsqrt safe.
__global__ void dinv_kernel(float* __restrict__ deg, int n) {
    int i = blockIdx.x * blockDim.x + threadIdx.x;
    if (i < n) deg[i] = rsqrtf(deg[i] + 1.0f);
}

// ---------------- exclusive scan of cnt -> start (3 kernels) ----------------

__global__ void scan1_kernel(const int* __restrict__ cnt, int* __restrict__ start,
                             int* __restrict__ bsum) {
    __shared__ int s[SCAN_B];
    int tid = threadIdx.x;
    int i = blockIdx.x * SCAN_B + tid;
    int c = (i < N_NODES) ? cnt[i] : 0;
    s[tid] = c;
    __syncthreads();
    for (int off = 1; off < SCAN_B; off <<= 1) {
        int v = (tid >= off) ? s[tid - off] : 0;
        __syncthreads();
        s[tid] += v;
        __syncthreads();
    }
    if (i < N_NODES) start[i] = s[tid] - c;        // intra-block exclusive
    if (tid == SCAN_B - 1) bsum[blockIdx.x] = s[tid];
}

__global__ void scan2_kernel(int* __restrict__ bsum) {
    __shared__ int s[512];
    int tid = threadIdx.x;
    int c = (tid < NB) ? bsum[tid] : 0;
    s[tid] = c;
    __syncthreads();
    for (int off = 1; off < 512; off <<= 1) {
        int v = (tid >= off) ? s[tid - off] : 0;
        __syncthreads();
        s[tid] += v;
        __syncthreads();
    }
    if (tid < NB) bsum[tid] = s[tid] - c;          // exclusive
}

__global__ void scan3_kernel(int* __restrict__ start, const int* __restrict__ bsum,
                             int* __restrict__ cursor) {
    int i = blockIdx.x * SCAN_B + threadIdx.x;
    if (i < N_NODES) {
        int v = start[i] + bsum[blockIdx.x];
        start[i] = v;
        cursor[i] = v;
    }
    if (i == 0) start[N_NODES] = N_EDGES;
}

// ---------------- fill CSR: packed[pos] = {src, norm} ----------------

__global__ void fill_kernel(const int* __restrict__ row, const int* __restrict__ col,
                            const float* __restrict__ ew, const float* __restrict__ dinv,
                            int* __restrict__ cursor, int2* __restrict__ packed, int E) {
    int e = blockIdx.x * blockDim.x + threadIdx.x;
    if (e >= E) return;
    int r = row[e], c = col[e];
    int pos = atomicAdd(&cursor[c], 1);
    float w = dinv[r] * ew[e] * dinv[c];
    packed[pos] = make_int2(r, __float_as_int(w));
}

// ---------------- GEMM1: h = x @ W1   [N,26] x [26,128] ----------------

__global__ void gemm1_kernel(const float* __restrict__ x, const float* __restrict__ W1,
                             float* __restrict__ h) {
    __shared__ float xs[16][N_CLASS];
    const int j  = threadIdx.x;
    const int nb = blockIdx.x * 16;
    for (int t = j; t < 16 * N_CLASS; t += 128) {
        int n = t / N_CLASS, k = t % N_CLASS;
        int node = nb + n;
        xs[n][k] = (node < N_NODES) ? x[node * N_CLASS + k] : 0.0f;
    }
    __syncthreads();
    float acc[16];
#pragma unroll
    for (int n = 0; n < 16; ++n) acc[n] = 0.0f;
#pragma unroll
    for (int k = 0; k < N_CLASS; ++k) {
        float w = W1[k * HIDDEN + j];
#pragma unroll
        for (int n = 0; n < 16; ++n) acc[n] += xs[n][k] * w;
    }
#pragma unroll
    for (int n = 0; n < 16; ++n) {
        int node = nb + n;
        if (node < N_NODES) h[(size_t)node * HIDDEN + j] = acc[n];
    }
}

// ---------------- CSR aggregation: out[g] = sum_in h[src]*w + h[g]*dinv[g]^2 ----------------
// 32 lanes per node (float4 each), 8 nodes per 256-thread block. No atomics.

__global__ __launch_bounds__(256) void gather_kernel(const float* __restrict__ h,
                                                     const int* __restrict__ start,
                                                     const int2* __restrict__ packed,
                                                     const float* __restrict__ dinv,
                                                     float* __restrict__ out) {
    int g = blockIdx.x * 8 + (threadIdx.x >> 5);
    if (g >= N_NODES) return;
    const int f = (threadIdx.x & 31) * 4;
    float ds = dinv[g];
    float wself = ds * ds;
    float4 acc = *reinterpret_cast<const float4*>(&h[(size_t)g * HIDDEN + f]);
    acc.x *= wself; acc.y *= wself; acc.z *= wself; acc.w *= wself;
    int s = start[g], t = start[g + 1];
    for (int i = s; i < t; ++i) {
        int2 p = packed[i];
        float w = __int_as_float(p.y);
        float4 v = *reinterpret_cast<const float4*>(&h[(size_t)p.x * HIDDEN + f]);
        acc.x += v.x * w; acc.y += v.y * w; acc.z += v.z * w; acc.w += v.w * w;
    }
    *reinterpret_cast<float4*>(&out[(size_t)g * HIDDEN + f]) = acc;
}

// ---------------- GEMM2: out = relu(xin + b) @ W   [N,128] x [128,128] ----------------

__global__ void gemm2_kernel(const float* __restrict__ xin, const float* __restrict__ b,
                             const float* __restrict__ W, float* __restrict__ out) {
    __shared__ float xs[16][HIDDEN];
    const int j  = threadIdx.x;
    const int nb = blockIdx.x * 16;
    for (int t = j; t < 16 * HIDDEN; t += 128) {
        int n = t >> 7, k = t & 127;
        int node = nb + n;
        xs[n][k] = (node < N_NODES) ? fmaxf(xin[(size_t)node * HIDDEN + k] + b[k], 0.0f) : 0.0f;
    }
    __syncthreads();
    float acc[16];
#pragma unroll
    for (int n = 0; n < 16; ++n) acc[n] = 0.0f;
    for (int k = 0; k < HIDDEN; ++k) {
        float w = W[k * HIDDEN + j];
#pragma unroll
        for (int n = 0; n < 16; ++n) acc[n] += xs[n][k] * w;
    }
#pragma unroll
    for (int n = 0; n < 16; ++n) {
        int node = nb + n;
        if (node < N_NODES) out[(size_t)node * HIDDEN + j] = acc[n];
    }
}

// ---------------- FC: out = relu(xin + b2) @ Wfc + bfc ----------------

__global__ void fc_kernel(const float* __restrict__ xin, const float* __restrict__ b2,
                          const float* __restrict__ Wfc, const float* __restrict__ bfc,
                          float* __restrict__ out) {
    __shared__ float xs[8][HIDDEN];
    __shared__ float wf[HIDDEN * N_CLASS];
    const int tid = threadIdx.x;
    const int nb  = blockIdx.x * 8;
    for (int t = tid; t < HIDDEN * N_CLASS; t += 256) wf[t] = Wfc[t];
    for (int t = tid; t < 8 * HIDDEN; t += 256) {
        int n = t >> 7, k = t & 127;
        int node = nb + n;
        xs[n][k] = (node < N_NODES) ? fmaxf(xin[(size_t)node * HIDDEN + k] + b2[k], 0.0f) : 0.0f;
    }
    __syncthreads();
    const int g = tid >> 5;
    const int j = tid & 31;
    const int node = nb + g;
    if (j < N_CLASS && node < N_NODES) {
        float acc = bfc[j];
#pragma unroll 8
        for (int k = 0; k < HIDDEN; ++k) acc += xs[g][k] * wf[k * N_CLASS + j];
        out[(size_t)node * N_CLASS + j] = acc;
    }
}

// ---------------- launch ----------------

extern "C" void kernel_launch(void* const* d_in, const int* in_sizes, int n_in,
                              void* d_out, int out_size, void* d_ws, size_t ws_size,
                              hipStream_t stream) {
    const float* x   = (const float*)d_in[0];
    const int*   ei  = (const int*)  d_in[1];
    const float* ew  = (const float*)d_in[2];
    const float* W1  = (const float*)d_in[3];
    const float* b1  = (const float*)d_in[4];
    const float* W2  = (const float*)d_in[5];
    const float* b2  = (const float*)d_in[6];
    const float* Wfc = (const float*)d_in[7];
    const float* bfc = (const float*)d_in[8];
    float* out = (float*)d_out;

    const int n = N_NODES, E = N_EDGES;
    const int* row = ei;        // edge_index[0] (sources)
    const int* col = ei + E;    // edge_index[1] (targets)

    char* ws = (char*)d_ws;
    size_t off = 0;
    auto alloc = [&](size_t bytes) -> void* {
        void* p = ws + off;
        off += (bytes + 255) & ~(size_t)255;
        return p;
    };
    float* dinv   = (float*)alloc((size_t)n * 4);
    int*   start  = (int*)  alloc((size_t)(n + 1) * 4);
    int*   cursor = (int*)  alloc((size_t)n * 4);        // doubles as histogram
    int*   bsum   = (int*)  alloc(512 * 4);
    int2*  packed = (int2*) alloc((size_t)E * 8);
    float* A      = (float*)alloc((size_t)n * HIDDEN * 4);
    float* B      = (float*)alloc((size_t)n * HIDDEN * 4);

    // degree + histogram
    hipMemsetAsync(dinv, 0, (size_t)n * 4, stream);
    hipMemsetAsync(cursor, 0, (size_t)n * 4, stream);
    deg_hist_kernel<<<(E + 255) / 256, 256, 0, stream>>>(col, ew, dinv, cursor, E);
    dinv_kernel<<<(n + 255) / 256, 256, 0, stream>>>(dinv, n);

    // exclusive scan cnt -> start; cursor = start
    scan1_kernel<<<NB, SCAN_B, 0, stream>>>(cursor, start, bsum);
    scan2_kernel<<<1, 512, 0, stream>>>(bsum);
    scan3_kernel<<<NB, SCAN_B, 0, stream>>>(start, bsum, cursor);

    // CSR fill (packed {src, norm})
    fill_kernel<<<(E + 255) / 256, 256, 0, stream>>>(row, col, ew, dinv, cursor, packed, E);

    // layer 1
    gemm1_kernel<<<(n + 15) / 16, 128, 0, stream>>>(x, W1, A);
    gather_kernel<<<(n + 7) / 8, 256, 0, stream>>>(A, start, packed, dinv, B);

    // layer 2
    gemm2_kernel<<<(n + 15) / 16, 128, 0, stream>>>(B, b1, W2, A);
    gather_kernel<<<(n + 7) / 8, 256, 0, stream>>>(A, start, packed, dinv, B);

    // final FC
    fc_kernel<<<(n + 7) / 8, 256, 0, stream>>>(B, b2, Wfc, bfc, out);
}

// Round 3
// 579.798 us; speedup vs baseline: 10.9667x; 1.8787x over previous
//
#include <hip/hip_runtime.h>

#define N_NODES 100000
#define N_EDGES 1600000
#define HIDDEN  128
#define N_CLASS 26
#define SCAN_B  256
#define NB ((N_NODES + SCAN_B - 1) / SCAN_B)   // 391 blocks

// ---------------- degree (float) + histogram (int) ----------------

__global__ void deg_hist_kernel(const int* __restrict__ col, const float* __restrict__ ew,
                                float* __restrict__ deg, int* __restrict__ cnt, int E) {
    int e = blockIdx.x * blockDim.x + threadIdx.x;
    if (e < E) {
        int c = col[e];
        atomicAdd(&deg[c], ew[e]);
        atomicAdd(&cnt[c], 1);
    }
}

__global__ void dinv_kernel(float* __restrict__ deg, int n) {
    int i = blockIdx.x * blockDim.x + threadIdx.x;
    if (i < n) deg[i] = rsqrtf(deg[i] + 1.0f);   // +1 self-loop
}

// ---------------- exclusive scan of cnt -> start ----------------

__global__ void scan1_kernel(const int* __restrict__ cnt, int* __restrict__ start,
                             int* __restrict__ bsum) {
    __shared__ int s[SCAN_B];
    int tid = threadIdx.x;
    int i = blockIdx.x * SCAN_B + tid;
    int c = (i < N_NODES) ? cnt[i] : 0;
    s[tid] = c;
    __syncthreads();
    for (int off = 1; off < SCAN_B; off <<= 1) {
        int v = (tid >= off) ? s[tid - off] : 0;
        __syncthreads();
        s[tid] += v;
        __syncthreads();
    }
    if (i < N_NODES) start[i] = s[tid] - c;
    if (tid == SCAN_B - 1) bsum[blockIdx.x] = s[tid];
}

__global__ void scan2_kernel(int* __restrict__ bsum) {
    __shared__ int s[512];
    int tid = threadIdx.x;
    int c = (tid < NB) ? bsum[tid] : 0;
    s[tid] = c;
    __syncthreads();
    for (int off = 1; off < 512; off <<= 1) {
        int v = (tid >= off) ? s[tid - off] : 0;
        __syncthreads();
        s[tid] += v;
        __syncthreads();
    }
    if (tid < NB) bsum[tid] = s[tid] - c;
}

__global__ void scan3_kernel(int* __restrict__ start, const int* __restrict__ bsum,
                             int* __restrict__ cursor) {
    int i = blockIdx.x * SCAN_B + threadIdx.x;
    if (i < N_NODES) {
        int v = start[i] + bsum[blockIdx.x];
        start[i] = v;
        cursor[i] = v;
    }
    if (i == 0) start[N_NODES] = N_EDGES;
}

// ---------------- fill CSR: packed[pos] = {src, norm} ----------------

__global__ void fill_kernel(const int* __restrict__ row, const int* __restrict__ col,
                            const float* __restrict__ ew, const float* __restrict__ dinv,
                            int* __restrict__ cursor, int2* __restrict__ packed, int E) {
    int e = blockIdx.x * blockDim.x + threadIdx.x;
    if (e >= E) return;
    int r = row[e], c = col[e];
    int pos = atomicAdd(&cursor[c], 1);
    float w = dinv[r] * ew[e] * dinv[c];
    packed[pos] = make_int2(r, __float_as_int(w));
}

// ---------------- gather26: aggx = S . x   (26-dim aggregation) ----------------
// 32 lanes/node (lane = feature, 26 active), 8 nodes per 256-thread block.

__global__ __launch_bounds__(256) void gather26_kernel(const float* __restrict__ x,
                                                       const int* __restrict__ start,
                                                       const int2* __restrict__ packed,
                                                       const float* __restrict__ dinv,
                                                       float* __restrict__ aggx) {
    int g = blockIdx.x * 8 + (threadIdx.x >> 5);
    if (g >= N_NODES) return;
    const int l = threadIdx.x & 31;
    const bool act = l < N_CLASS;
    float ds = dinv[g];
    float acc = act ? x[(size_t)g * N_CLASS + l] * ds * ds : 0.0f;
    int s = start[g], t = start[g + 1];
    for (int i = s; i < t; ++i) {
        int2 p = packed[i];
        float w = __int_as_float(p.y);
        if (act) acc += x[(size_t)p.x * N_CLASS + l] * w;
    }
    if (act) aggx[(size_t)g * N_CLASS + l] = acc;
}

// ---------------- gemmB: h1 = relu(aggx @ W1 + b1)   [N,26]x[26,128] ----------------
// 64 nodes/block, 256 threads; W1 column in registers, aggx tile in LDS.

__global__ __launch_bounds__(256) void gemmB_kernel(const float* __restrict__ aggx,
                                                    const float* __restrict__ W1,
                                                    const float* __restrict__ b1,
                                                    float* __restrict__ h1) {
    __shared__ float axs[64 * N_CLASS];
    const int tid = threadIdx.x;
    const int nb = blockIdx.x * 64;
    for (int t = tid; t < 64 * N_CLASS; t += 256) {
        size_t idx = (size_t)nb * N_CLASS + t;
        axs[t] = (idx < (size_t)N_NODES * N_CLASS) ? aggx[idx] : 0.0f;
    }
    const int c  = tid & 127;
    const int nr = tid >> 7;            // 0..1
    float w[N_CLASS];
#pragma unroll
    for (int k = 0; k < N_CLASS; ++k) w[k] = W1[k * HIDDEN + c];
    const float bias = b1[c];
    __syncthreads();
    for (int t = 0; t < 32; ++t) {
        int n = nr + 2 * t;
        int node = nb + n;
        if (node >= N_NODES) break;
        float acc = bias;
#pragma unroll
        for (int k = 0; k < N_CLASS; ++k) acc += axs[n * N_CLASS + k] * w[k];
        h1[(size_t)node * HIDDEN + c] = fmaxf(acc, 0.0f);
    }
}

// ---------------- gemmC: p = h1 @ W2   [N,128]x[128,128] ----------------
// 128 nodes/block, 512 threads; W2 + h1 tile in LDS; thread = 8 nodes x 4 cols.

#define CB_NODES 128
__global__ __launch_bounds__(512) void gemmC_kernel(const float* __restrict__ h1,
                                                    const float* __restrict__ W2,
                                                    float* __restrict__ p) {
    __shared__ float hs[CB_NODES][HIDDEN];   // 64 KB
    __shared__ float ws[HIDDEN][HIDDEN];     // 64 KB
    const int tid = threadIdx.x;
    const int nb = blockIdx.x * CB_NODES;
    for (int t = tid; t < HIDDEN * HIDDEN / 4; t += 512)
        reinterpret_cast<float4*>(ws)[t] = reinterpret_cast<const float4*>(W2)[t];
    for (int t = tid; t < CB_NODES * HIDDEN / 4; t += 512) {
        int node = nb + t / (HIDDEN / 4);
        reinterpret_cast<float4*>(hs)[t] =
            (node < N_NODES)
                ? reinterpret_cast<const float4*>(h1)[(size_t)node * (HIDDEN / 4) + (t & (HIDDEN / 4 - 1))]
                : make_float4(0.f, 0.f, 0.f, 0.f);
    }
    __syncthreads();
    const int c4 = (tid & 31) * 4;
    const int n0 = (tid >> 5) * 8;      // 0..120
    float acc[8][4] = {};
    for (int k4 = 0; k4 < HIDDEN; k4 += 4) {
        float4 wv[4];
#pragma unroll
        for (int kk = 0; kk < 4; ++kk)
            wv[kk] = *reinterpret_cast<const float4*>(&ws[k4 + kk][c4]);
#pragma unroll
        for (int i = 0; i < 8; ++i) {
            float4 hv = *reinterpret_cast<const float4*>(&hs[n0 + i][k4]);
            acc[i][0] += hv.x * wv[0].x + hv.y * wv[1].x + hv.z * wv[2].x + hv.w * wv[3].x;
            acc[i][1] += hv.x * wv[0].y + hv.y * wv[1].y + hv.z * wv[2].y + hv.w * wv[3].y;
            acc[i][2] += hv.x * wv[0].z + hv.y * wv[1].z + hv.z * wv[2].z + hv.w * wv[3].z;
            acc[i][3] += hv.x * wv[0].w + hv.y * wv[1].w + hv.z * wv[2].w + hv.w * wv[3].w;
        }
    }
#pragma unroll
    for (int i = 0; i < 8; ++i) {
        int node = nb + n0 + i;
        if (node < N_NODES) {
            float4 v = make_float4(acc[i][0], acc[i][1], acc[i][2], acc[i][3]);
            *reinterpret_cast<float4*>(&p[(size_t)node * HIDDEN + c4]) = v;
        }
    }
}

// ---------------- aggfc: out = relu(S.p + b2) @ Wfc + bfc (fused) ----------------
// 32 lanes/node (float4 each), 8 nodes per 256-thread block; Wfc in LDS.

__global__ __launch_bounds__(256) void aggfc_kernel(const float* __restrict__ p,
                                                    const int* __restrict__ start,
                                                    const int2* __restrict__ packed,
                                                    const float* __restrict__ dinv,
                                                    const float* __restrict__ b2,
                                                    const float* __restrict__ Wfc,
                                                    const float* __restrict__ bfc,
                                                    float* __restrict__ out) {
    __shared__ float wfs[HIDDEN * N_CLASS];
    __shared__ float bfs[N_CLASS];
    __shared__ float zs[8][HIDDEN];
    const int tid = threadIdx.x;
    for (int t = tid; t < HIDDEN * N_CLASS; t += 256) wfs[t] = Wfc[t];
    if (tid < N_CLASS) bfs[tid] = bfc[tid];
    __syncthreads();

    const int grp = tid >> 5;
    const int l   = tid & 31;
    const int g   = blockIdx.x * 8 + grp;   // 12500*8 == 100000 exactly
    const int f   = l * 4;

    float ds = dinv[g];
    float wself = ds * ds;
    float4 acc = *reinterpret_cast<const float4*>(&p[(size_t)g * HIDDEN + f]);
    acc.x *= wself; acc.y *= wself; acc.z *= wself; acc.w *= wself;
    int s = start[g], t = start[g + 1];
    for (int i = s; i < t; ++i) {
        int2 pk = packed[i];
        float w = __int_as_float(pk.y);
        float4 v = *reinterpret_cast<const float4*>(&p[(size_t)pk.x * HIDDEN + f]);
        acc.x += v.x * w; acc.y += v.y * w; acc.z += v.z * w; acc.w += v.w * w;
    }
    float4 bz = *reinterpret_cast<const float4*>(&b2[f]);
    float4 z = make_float4(fmaxf(acc.x + bz.x, 0.f), fmaxf(acc.y + bz.y, 0.f),
                           fmaxf(acc.z + bz.z, 0.f), fmaxf(acc.w + bz.w, 0.f));
    *reinterpret_cast<float4*>(&zs[grp][f]) = z;
    // groups are half-waves: lanes are lockstep; compiler inserts lgkmcnt for zs reuse.
    if (l < N_CLASS) {
        float acc2 = bfs[l];
#pragma unroll 8
        for (int k = 0; k < HIDDEN; ++k) acc2 += zs[grp][k] * wfs[k * N_CLASS + l];
        out[(size_t)g * N_CLASS + l] = acc2;
    }
}

// ---------------- launch ----------------

extern "C" void kernel_launch(void* const* d_in, const int* in_sizes, int n_in,
                              void* d_out, int out_size, void* d_ws, size_t ws_size,
                              hipStream_t stream) {
    const float* x   = (const float*)d_in[0];
    const int*   ei  = (const int*)  d_in[1];
    const float* ew  = (const float*)d_in[2];
    const float* W1  = (const float*)d_in[3];
    const float* b1  = (const float*)d_in[4];
    const float* W2  = (const float*)d_in[5];
    const float* b2  = (const float*)d_in[6];
    const float* Wfc = (const float*)d_in[7];
    const float* bfc = (const float*)d_in[8];
    float* out = (float*)d_out;

    const int n = N_NODES, E = N_EDGES;
    const int* row = ei;
    const int* col = ei + E;

    char* ws = (char*)d_ws;
    size_t off = 0;
    auto alloc = [&](size_t bytes) -> void* {
        void* ptr = ws + off;
        off += (bytes + 255) & ~(size_t)255;
        return ptr;
    };
    float* dinv   = (float*)alloc((size_t)n * 4);
    int*   start  = (int*)  alloc((size_t)(n + 1) * 4);
    int*   cursor = (int*)  alloc((size_t)n * 4);
    int*   bsum   = (int*)  alloc(512 * 4);
    int2*  packed = (int2*) alloc((size_t)E * 8);
    float* aggx   = (float*)alloc((size_t)n * N_CLASS * 4);
    float* h1     = (float*)alloc((size_t)n * HIDDEN * 4);
    float* p      = (float*)alloc((size_t)n * HIDDEN * 4);

    hipMemsetAsync(dinv, 0, (size_t)n * 4, stream);
    hipMemsetAsync(cursor, 0, (size_t)n * 4, stream);
    deg_hist_kernel<<<(E + 255) / 256, 256, 0, stream>>>(col, ew, dinv, cursor, E);
    dinv_kernel<<<(n + 255) / 256, 256, 0, stream>>>(dinv, n);

    scan1_kernel<<<NB, SCAN_B, 0, stream>>>(cursor, start, bsum);
    scan2_kernel<<<1, 512, 0, stream>>>(bsum);
    scan3_kernel<<<NB, SCAN_B, 0, stream>>>(start, bsum, cursor);

    fill_kernel<<<(E + 255) / 256, 256, 0, stream>>>(row, col, ew, dinv, cursor, packed, E);

    // layer 1 (aggregate in 26-dim, then GEMM with fused bias+relu)
    gather26_kernel<<<(n + 7) / 8, 256, 0, stream>>>(x, start, packed, dinv, aggx);
    gemmB_kernel<<<(n + 63) / 64, 256, 0, stream>>>(aggx, W1, b1, h1);

    // layer 2 (GEMM first, then fused aggregate + bias + relu + FC)
    gemmC_kernel<<<(n + CB_NODES - 1) / CB_NODES, 512, 0, stream>>>(h1, W2, p);
    aggfc_kernel<<<(n + 7) / 8, 256, 0, stream>>>(p, start, packed, dinv, b2, Wfc, bfc, out);
}

// Round 4
// 440.364 us; speedup vs baseline: 14.4391x; 1.3166x over previous
//
#include <hip/hip_runtime.h>
#include <hip/hip_fp16.h>

#define N_NODES 100000
#define N_EDGES 1600000
#define HIDDEN  128
#define N_CLASS 26
#define SCAN_B  256
#define NB ((N_NODES + SCAN_B - 1) / SCAN_B)   // 391 blocks

struct h4v { __half2 a, b; };   // 8 bytes = 4 halves

// ---------------- histogram: cnt (hi32) | deg in 2^-24 fixed point (lo32) ----------------

__global__ void hist_kernel(const int* __restrict__ col, const float* __restrict__ ew,
                            unsigned long long* __restrict__ hist, int E) {
    int e = blockIdx.x * blockDim.x + threadIdx.x;
    if (e < E) {
        unsigned int q = __float2uint_rn(ew[e] * 16777216.0f);
        atomicAdd(&hist[col[e]], 0x100000000ULL | (unsigned long long)q);
    }
}

__global__ void dinv_kernel(const unsigned long long* __restrict__ hist,
                            float* __restrict__ dinv, int n) {
    int i = blockIdx.x * blockDim.x + threadIdx.x;
    if (i < n) {
        float deg = (float)(unsigned int)(hist[i] & 0xFFFFFFFFULL) * (1.0f / 16777216.0f);
        dinv[i] = rsqrtf(deg + 1.0f);   // +1 self-loop
    }
}

// ---------------- exclusive scan of cnt -> start ----------------

__global__ void scan1_kernel(const unsigned long long* __restrict__ hist,
                             int* __restrict__ start, int* __restrict__ bsum) {
    __shared__ int s[SCAN_B];
    int tid = threadIdx.x;
    int i = blockIdx.x * SCAN_B + tid;
    int c = (i < N_NODES) ? (int)(hist[i] >> 32) : 0;
    s[tid] = c;
    __syncthreads();
    for (int off = 1; off < SCAN_B; off <<= 1) {
        int v = (tid >= off) ? s[tid - off] : 0;
        __syncthreads();
        s[tid] += v;
        __syncthreads();
    }
    if (i < N_NODES) start[i] = s[tid] - c;
    if (tid == SCAN_B - 1) bsum[blockIdx.x] = s[tid];
}

__global__ void scan2_kernel(int* __restrict__ bsum) {
    __shared__ int s[512];
    int tid = threadIdx.x;
    int c = (tid < NB) ? bsum[tid] : 0;
    s[tid] = c;
    __syncthreads();
    for (int off = 1; off < 512; off <<= 1) {
        int v = (tid >= off) ? s[tid - off] : 0;
        __syncthreads();
        s[tid] += v;
        __syncthreads();
    }
    if (tid < NB) bsum[tid] = s[tid] - c;
}

__global__ void scan3_kernel(int* __restrict__ start, const int* __restrict__ bsum,
                             int* __restrict__ cursor) {
    int i = blockIdx.x * SCAN_B + threadIdx.x;
    if (i < N_NODES) {
        int v = start[i] + bsum[blockIdx.x];
        start[i] = v;
        cursor[i] = v;
    }
    if (i == 0) start[N_NODES] = N_EDGES;
}

// ---------------- fill CSR: packed[pos] = {src, ew}  (no dinv needed) ----------------

__global__ void fill_kernel(const int* __restrict__ row, const int* __restrict__ col,
                            const float* __restrict__ ew,
                            int* __restrict__ cursor, int2* __restrict__ packed, int E) {
    int e = blockIdx.x * blockDim.x + threadIdx.x;
    if (e >= E) return;
    int pos = atomicAdd(&cursor[col[e]], 1);
    packed[pos] = make_int2(row[e], __float_as_int(ew[e]));
}

// ---------------- xconv: x16[v][l] = fp16(x[v][l] * dinv[v]), padded to 32 ----------------

__global__ void xconv_kernel(const float* __restrict__ x, const float* __restrict__ dinv,
                             __half* __restrict__ x16) {
    int idx = blockIdx.x * blockDim.x + threadIdx.x;   // N*32 threads
    int node = idx >> 5, l = idx & 31;
    float v = 0.0f;
    if (l < N_CLASS) v = x[(size_t)node * N_CLASS + l] * dinv[node];
    x16[idx] = __float2half(v);
}

// ---------------- gather26: aggx[g] = dinv[g]*(x16[g] + sum ew*x16[src]) ----------------
// 32 lanes/node (lane = padded feature), 8 nodes per 256-thread block, unroll 4.

__global__ __launch_bounds__(256) void gather26_kernel(const __half* __restrict__ x16,
                                                       const int* __restrict__ start,
                                                       const int2* __restrict__ packed,
                                                       const float* __restrict__ dinv,
                                                       float* __restrict__ aggx) {
    int g = blockIdx.x * 8 + (threadIdx.x >> 5);   // 12500*8 == 100000 exactly
    const int l = threadIdx.x & 31;
    float acc = __half2float(x16[((size_t)g << 5) + l]);   // self-loop, ew=1
    int s = start[g], t = start[g + 1];
    int i = s;
    for (; i + 4 <= t; i += 4) {
        int2 p0 = packed[i], p1 = packed[i + 1], p2 = packed[i + 2], p3 = packed[i + 3];
        float v0 = __half2float(x16[((size_t)p0.x << 5) + l]);
        float v1 = __half2float(x16[((size_t)p1.x << 5) + l]);
        float v2 = __half2float(x16[((size_t)p2.x << 5) + l]);
        float v3 = __half2float(x16[((size_t)p3.x << 5) + l]);
        acc += __int_as_float(p0.y) * v0 + __int_as_float(p1.y) * v1
             + __int_as_float(p2.y) * v2 + __int_as_float(p3.y) * v3;
    }
    for (; i < t; ++i) {
        int2 p = packed[i];
        acc += __int_as_float(p.y) * __half2float(x16[((size_t)p.x << 5) + l]);
    }
    aggx[((size_t)g << 5) + l] = dinv[g] * acc;
}

// ---------------- gemmB: h1 = relu(aggx @ W1 + b1)   [N,26(pad32)]x[26,128] ----------------

__global__ __launch_bounds__(256) void gemmB_kernel(const float* __restrict__ aggx,
                                                    const float* __restrict__ W1,
                                                    const float* __restrict__ b1,
                                                    float* __restrict__ h1) {
    __shared__ float axs[64][32];
    const int tid = threadIdx.x;
    const int nb = blockIdx.x * 64;
    for (int t = tid; t < 64 * 32 / 4; t += 256) {
        int node = nb + (t >> 3);
        reinterpret_cast<float4*>(axs)[t] =
            (node < N_NODES)
                ? reinterpret_cast<const float4*>(aggx)[((size_t)node << 3) + (t & 7)]
                : make_float4(0.f, 0.f, 0.f, 0.f);
    }
    const int c  = tid & 127;
    const int nr = tid >> 7;
    float w[N_CLASS];
#pragma unroll
    for (int k = 0; k < N_CLASS; ++k) w[k] = W1[k * HIDDEN + c];
    const float bias = b1[c];
    __syncthreads();
    for (int tt = 0; tt < 32; ++tt) {
        int n = nr + 2 * tt;
        int node = nb + n;
        if (node < N_NODES) {
            float acc = bias;
#pragma unroll
            for (int k = 0; k < N_CLASS; ++k) acc += axs[n][k] * w[k];
            h1[(size_t)node * HIDDEN + c] = fmaxf(acc, 0.0f);
        }
    }
}

// ---------------- gemmC: p16 = fp16(dinv * (h1 @ W2))   [N,128]x[128,128] ----------------

#define CB_NODES 128
__global__ __launch_bounds__(512) void gemmC_kernel(const float* __restrict__ h1,
                                                    const float* __restrict__ W2,
                                                    const float* __restrict__ dinv,
                                                    __half* __restrict__ p16) {
    __shared__ float hs[CB_NODES][HIDDEN];   // 64 KB
    __shared__ float ws[HIDDEN][HIDDEN];     // 64 KB
    const int tid = threadIdx.x;
    const int nb = blockIdx.x * CB_NODES;
    for (int t = tid; t < HIDDEN * HIDDEN / 4; t += 512)
        reinterpret_cast<float4*>(ws)[t] = reinterpret_cast<const float4*>(W2)[t];
    for (int t = tid; t < CB_NODES * HIDDEN / 4; t += 512) {
        int node = nb + t / (HIDDEN / 4);
        reinterpret_cast<float4*>(hs)[t] =
            (node < N_NODES)
                ? reinterpret_cast<const float4*>(h1)[(size_t)node * (HIDDEN / 4) + (t & (HIDDEN / 4 - 1))]
                : make_float4(0.f, 0.f, 0.f, 0.f);
    }
    __syncthreads();
    const int c4 = (tid & 31) * 4;
    const int n0 = (tid >> 5) * 8;
    float acc[8][4] = {};
    for (int k4 = 0; k4 < HIDDEN; k4 += 4) {
        float4 wv[4];
#pragma unroll
        for (int kk = 0; kk < 4; ++kk)
            wv[kk] = *reinterpret_cast<const float4*>(&ws[k4 + kk][c4]);
#pragma unroll
        for (int i = 0; i < 8; ++i) {
            float4 hv = *reinterpret_cast<const float4*>(&hs[n0 + i][k4]);
            acc[i][0] += hv.x * wv[0].x + hv.y * wv[1].x + hv.z * wv[2].x + hv.w * wv[3].x;
            acc[i][1] += hv.x * wv[0].y + hv.y * wv[1].y + hv.z * wv[2].y + hv.w * wv[3].y;
            acc[i][2] += hv.x * wv[0].z + hv.y * wv[1].z + hv.z * wv[2].z + hv.w * wv[3].z;
            acc[i][3] += hv.x * wv[0].w + hv.y * wv[1].w + hv.z * wv[2].w + hv.w * wv[3].w;
        }
    }
#pragma unroll
    for (int i = 0; i < 8; ++i) {
        int node = nb + n0 + i;
        if (node < N_NODES) {
            float d = dinv[node];
            union { __half2 h2[2]; uint2 u; } pk;
            pk.h2[0] = __floats2half2_rn(d * acc[i][0], d * acc[i][1]);
            pk.h2[1] = __floats2half2_rn(d * acc[i][2], d * acc[i][3]);
            *reinterpret_cast<uint2*>(&p16[(size_t)node * HIDDEN + c4]) = pk.u;
        }
    }
}

// ---------------- aggfc: out = relu(dinv*(p16[g] + sum ew*p16[src]) + b2) @ Wfc + bfc ----------------
// 32 lanes/node (4 halves each), 8 nodes per 256-thread block, unroll 4; Wfc in LDS.

__global__ __launch_bounds__(256) void aggfc_kernel(const __half* __restrict__ p16,
                                                    const int* __restrict__ start,
                                                    const int2* __restrict__ packed,
                                                    const float* __restrict__ dinv,
                                                    const float* __restrict__ b2,
                                                    const float* __restrict__ Wfc,
                                                    const float* __restrict__ bfc,
                                                    float* __restrict__ out) {
    __shared__ float wfs[HIDDEN * N_CLASS];
    __shared__ float bfs[N_CLASS];
    __shared__ float zs[8][HIDDEN];
    const int tid = threadIdx.x;
    for (int t = tid; t < HIDDEN * N_CLASS; t += 256) wfs[t] = Wfc[t];
    if (tid < N_CLASS) bfs[tid] = bfc[tid];
    __syncthreads();

    const int grp = tid >> 5;
    const int l   = tid & 31;
    const int g   = blockIdx.x * 8 + grp;   // 12500*8 == 100000 exactly
    const int f   = l * 4;
    const h4v* P  = reinterpret_cast<const h4v*>(p16);

    h4v vs = P[((size_t)g << 5) + l];       // self-loop, ew=1
    float2 s01 = __half22float2(vs.a), s23 = __half22float2(vs.b);
    float4 acc = make_float4(s01.x, s01.y, s23.x, s23.y);

    int s = start[g], t = start[g + 1];
    int i = s;
    for (; i + 4 <= t; i += 4) {
        int2 p0 = packed[i], p1 = packed[i + 1], p2 = packed[i + 2], p3 = packed[i + 3];
        h4v v0 = P[((size_t)p0.x << 5) + l];
        h4v v1 = P[((size_t)p1.x << 5) + l];
        h4v v2 = P[((size_t)p2.x << 5) + l];
        h4v v3 = P[((size_t)p3.x << 5) + l];
        float w0 = __int_as_float(p0.y), w1 = __int_as_float(p1.y);
        float w2 = __int_as_float(p2.y), w3 = __int_as_float(p3.y);
        float2 a0 = __half22float2(v0.a), b0 = __half22float2(v0.b);
        float2 a1 = __half22float2(v1.a), b1_ = __half22float2(v1.b);
        float2 a2 = __half22float2(v2.a), b2_ = __half22float2(v2.b);
        float2 a3 = __half22float2(v3.a), b3_ = __half22float2(v3.b);
        acc.x += w0 * a0.x + w1 * a1.x + w2 * a2.x + w3 * a3.x;
        acc.y += w0 * a0.y + w1 * a1.y + w2 * a2.y + w3 * a3.y;
        acc.z += w0 * b0.x + w1 * b1_.x + w2 * b2_.x + w3 * b3_.x;
        acc.w += w0 * b0.y + w1 * b1_.y + w2 * b2_.y + w3 * b3_.y;
    }
    for (; i < t; ++i) {
        int2 p = packed[i];
        float w = __int_as_float(p.y);
        h4v v = P[((size_t)p.x << 5) + l];
        float2 a = __half22float2(v.a), b = __half22float2(v.b);
        acc.x += w * a.x; acc.y += w * a.y; acc.z += w * b.x; acc.w += w * b.y;
    }

    float dg = dinv[g];
    float4 bz = *reinterpret_cast<const float4*>(&b2[f]);
    float4 z = make_float4(fmaxf(dg * acc.x + bz.x, 0.f), fmaxf(dg * acc.y + bz.y, 0.f),
                           fmaxf(dg * acc.z + bz.z, 0.f), fmaxf(dg * acc.w + bz.w, 0.f));
    *reinterpret_cast<float4*>(&zs[grp][f]) = z;
    if (l < N_CLASS) {
        float acc2 = bfs[l];
#pragma unroll 8
        for (int k = 0; k < HIDDEN; ++k) acc2 += zs[grp][k] * wfs[k * N_CLASS + l];
        out[(size_t)g * N_CLASS + l] = acc2;
    }
}

// ---------------- launch ----------------

extern "C" void kernel_launch(void* const* d_in, const int* in_sizes, int n_in,
                              void* d_out, int out_size, void* d_ws, size_t ws_size,
                              hipStream_t stream) {
    const float* x   = (const float*)d_in[0];
    const int*   ei  = (const int*)  d_in[1];
    const float* ew  = (const float*)d_in[2];
    const float* W1  = (const float*)d_in[3];
    const float* b1  = (const float*)d_in[4];
    const float* W2  = (const float*)d_in[5];
    const float* b2  = (const float*)d_in[6];
    const float* Wfc = (const float*)d_in[7];
    const float* bfc = (const float*)d_in[8];
    float* out = (float*)d_out;

    const int n = N_NODES, E = N_EDGES;
    const int* row = ei;
    const int* col = ei + E;

    char* ws = (char*)d_ws;
    size_t off = 0;
    auto alloc = [&](size_t bytes) -> void* {
        void* ptr = ws + off;
        off += (bytes + 255) & ~(size_t)255;
        return ptr;
    };
    unsigned long long* hist = (unsigned long long*)alloc((size_t)n * 8);
    float* dinv   = (float*)alloc((size_t)n * 4);
    int*   start  = (int*)  alloc((size_t)(n + 1) * 4);
    int*   cursor = (int*)  alloc((size_t)n * 4);
    int*   bsum   = (int*)  alloc(512 * 4);
    int2*  packed = (int2*) alloc((size_t)E * 8);
    __half* x16   = (__half*)alloc((size_t)n * 32 * 2);
    float* aggx   = (float*)alloc((size_t)n * 32 * 4);
    float* h1     = (float*)alloc((size_t)n * HIDDEN * 4);
    __half* p16   = (__half*)alloc((size_t)n * HIDDEN * 2);

    hipMemsetAsync(hist, 0, (size_t)n * 8, stream);
    hist_kernel<<<(E + 255) / 256, 256, 0, stream>>>(col, ew, hist, E);
    dinv_kernel<<<(n + 255) / 256, 256, 0, stream>>>(hist, dinv, n);

    scan1_kernel<<<NB, SCAN_B, 0, stream>>>(hist, start, bsum);
    scan2_kernel<<<1, 512, 0, stream>>>(bsum);
    scan3_kernel<<<NB, SCAN_B, 0, stream>>>(start, bsum, cursor);

    fill_kernel<<<(E + 255) / 256, 256, 0, stream>>>(row, col, ew, cursor, packed, E);

    xconv_kernel<<<(n * 32) / 256, 256, 0, stream>>>(x, dinv, x16);

    // layer 1
    gather26_kernel<<<(n + 7) / 8, 256, 0, stream>>>(x16, start, packed, dinv, aggx);
    gemmB_kernel<<<(n + 63) / 64, 256, 0, stream>>>(aggx, W1, b1, h1);

    // layer 2 + FC
    gemmC_kernel<<<(n + CB_NODES - 1) / CB_NODES, 512, 0, stream>>>(h1, W2, dinv, p16);
    aggfc_kernel<<<(n + 7) / 8, 256, 0, stream>>>(p16, start, packed, dinv, b2, Wfc, bfc, out);
}

// Round 5
// 281.584 us; speedup vs baseline: 22.5811x; 1.5639x over previous
//
#include <hip/hip_runtime.h>
#include <hip/hip_fp16.h>

#define N_NODES 100000
#define N_EDGES 1600000
#define HIDDEN  128
#define N_CLASS 26

#define BUK_SHIFT 9
#define BUK_DSTS  512
#define NBUK      196            // ceil(100000/512)
#define BUK_CAP   10240          // avg 8163, +23 sigma headroom
#define PB_EDGES  8192
#define PB_BLOCKS ((N_EDGES + PB_EDGES - 1) / PB_EDGES)   // 196

struct h4v { __half2 a, b; };   // 8 bytes = 4 halves

// ---------------- pass B: bucket edges by dst>>9 with coalesced run writes ----------------

__global__ __launch_bounds__(1024) void bucket_kernel(const int* __restrict__ row,
                                                      const int* __restrict__ col,
                                                      const float* __restrict__ ew,
                                                      int* __restrict__ bukcnt,
                                                      int2* __restrict__ stage) {
    __shared__ int2 outst[PB_EDGES];            // 64 KB
    __shared__ unsigned short bukof[PB_EDGES];  // 16 KB
    __shared__ int cnt[NBUK], ofs[NBUK], cur[NBUK], gt[NBUK];
    __shared__ int sc[256];
    const int tid = threadIdx.x;
    const int e0 = blockIdx.x * PB_EDGES;
    const int nvalid = min(PB_EDGES, N_EDGES - e0);

    for (int b = tid; b < NBUK; b += 1024) { cnt[b] = 0; cur[b] = 0; }
    __syncthreads();

    int mykey[8]; float myw[8]; int mybuk[8];
#pragma unroll
    for (int i = 0; i < 8; ++i) {
        int idx = tid + i * 1024;                 // coalesced
        mybuk[i] = -1;
        if (idx < nvalid) {
            int e = e0 + idx;
            int d = col[e], r = row[e];
            int buk = d >> BUK_SHIFT;
            mykey[i] = ((d & (BUK_DSTS - 1)) << 17) | r;
            myw[i] = ew[e];
            mybuk[i] = buk;
            atomicAdd(&cnt[buk], 1);
        }
    }
    __syncthreads();

    // exclusive scan cnt[196] -> ofs (Hillis-Steele over 256 lanes)
    {
        int c = (tid < NBUK) ? cnt[tid] : 0;
        if (tid < 256) sc[tid] = c;
        __syncthreads();
        for (int o = 1; o < 256; o <<= 1) {
            int v = 0;
            if (tid < 256 && tid >= o) v = sc[tid - o];
            __syncthreads();
            if (tid < 256) sc[tid] += v;
            __syncthreads();
        }
        if (tid < NBUK) ofs[tid] = sc[tid] - c;
        __syncthreads();
    }

    // place entries into LDS out-stage grouped by bucket
#pragma unroll
    for (int i = 0; i < 8; ++i) {
        if (mybuk[i] >= 0) {
            int s = ofs[mybuk[i]] + atomicAdd(&cur[mybuk[i]], 1);
            outst[s] = make_int2(mykey[i], __float_as_int(myw[i]));
            bukof[s] = (unsigned short)mybuk[i];
        }
    }
    __syncthreads();

    // reserve global runs (one atomic per bucket per block)
    if (tid < NBUK) {
        int c = cnt[tid];
        int gb = (c > 0) ? atomicAdd(&bukcnt[tid], c) : 0;
        gt[tid] = tid * BUK_CAP + gb;
    }
    __syncthreads();

    // coalesced flush: consecutive i -> mostly consecutive global addresses
    for (int i = tid; i < nvalid; i += 1024) {
        int b = bukof[i];
        stage[(size_t)gt[b] + (i - ofs[b])] = outst[i];
    }
}

// ---------------- scan bucket totals -> compact CSR bases ----------------

__global__ void bukscan_kernel(const int* __restrict__ bukcnt, int* __restrict__ bukbase,
                               int* __restrict__ start) {
    __shared__ int s[256];
    int tid = threadIdx.x;
    int c = (tid < NBUK) ? bukcnt[tid] : 0;
    s[tid] = c;
    __syncthreads();
    for (int o = 1; o < 256; o <<= 1) {
        int v = (tid >= o) ? s[tid - o] : 0;
        __syncthreads();
        s[tid] += v;
        __syncthreads();
    }
    if (tid < NBUK) bukbase[tid] = s[tid] - c;
    if (tid == 0) start[N_NODES] = N_EDGES;
}

// ---------------- pass C: per-bucket CSR + dinv + x16, all writes L2-local ----------------

__global__ __launch_bounds__(1024) void csr_kernel(const int2* __restrict__ stage,
                                                   const int* __restrict__ bukcnt,
                                                   const int* __restrict__ bukbase,
                                                   const float* __restrict__ x,
                                                   int* __restrict__ start,
                                                   float* __restrict__ dinv,
                                                   __half* __restrict__ x16,
                                                   int2* __restrict__ packed) {
    __shared__ unsigned int cnt5[BUK_DSTS];
    __shared__ int ofs5[BUK_DSTS];
    __shared__ unsigned int cur5[BUK_DSTS];
    __shared__ float deg5[BUK_DSTS];
    __shared__ float dv5[BUK_DSTS];
    __shared__ int sc[BUK_DSTS];
    const int tid = threadIdx.x;
    const int b = blockIdx.x;
    const int total = bukcnt[b];
    const int base = bukbase[b];
    const int2* st = stage + (size_t)b * BUK_CAP;

    for (int j = tid; j < BUK_DSTS; j += 1024) { cnt5[j] = 0; cur5[j] = 0; deg5[j] = 0.0f; }
    __syncthreads();

    for (int i = tid; i < total; i += 1024) {
        int2 en = st[i];
        int dl = en.x >> 17;
        atomicAdd(&cnt5[dl], 1u);
        atomicAdd(&deg5[dl], __int_as_float(en.y));
    }
    __syncthreads();

    // exclusive scan cnt5[512] -> ofs5
    {
        int c = (tid < BUK_DSTS) ? (int)cnt5[tid] : 0;
        if (tid < BUK_DSTS) sc[tid] = c;
        __syncthreads();
        for (int o = 1; o < BUK_DSTS; o <<= 1) {
            int v = 0;
            if (tid < BUK_DSTS && tid >= o) v = sc[tid - o];
            __syncthreads();
            if (tid < BUK_DSTS) sc[tid] += v;
            __syncthreads();
        }
        if (tid < BUK_DSTS) ofs5[tid] = sc[tid] - c;
        __syncthreads();
    }

    // per-dst start + dinv
    if (tid < BUK_DSTS) {
        int d = (b << BUK_SHIFT) + tid;
        if (d < N_NODES) {
            float dv = rsqrtf(deg5[tid] + 1.0f);    // +1 self-loop
            dv5[tid] = dv;
            dinv[d] = dv;
            start[d] = base + ofs5[tid];
        }
    }
    __syncthreads();

    // x16 rows (prescaled by dinv, padded to 32) for this bucket's nodes
    for (int t = tid; t < BUK_DSTS * 32; t += 1024) {
        int j = t >> 5, l = t & 31;
        int d = (b << BUK_SHIFT) + j;
        if (d < N_NODES) {
            float v = (l < N_CLASS) ? x[(size_t)d * N_CLASS + l] * dv5[j] : 0.0f;
            x16[((size_t)d << 5) + l] = __float2half(v);
        }
    }

    // scatter into compact CSR region (L2-local to this block's XCD)
    for (int i = tid; i < total; i += 1024) {
        int2 en = st[i];
        int dl = en.x >> 17;
        int src = en.x & 0x1FFFF;
        unsigned int r = atomicAdd(&cur5[dl], 1u);
        packed[(size_t)base + ofs5[dl] + (int)r] = make_int2(src, en.y);
    }
}

// ---------------- gather26: aggx[g] = dinv[g]*(x16[g] + sum ew*x16[src]) ----------------

__global__ __launch_bounds__(256) void gather26_kernel(const __half* __restrict__ x16,
                                                       const int* __restrict__ start,
                                                       const int2* __restrict__ packed,
                                                       const float* __restrict__ dinv,
                                                       float* __restrict__ aggx) {
    int g = blockIdx.x * 8 + (threadIdx.x >> 5);   // 12500*8 == 100000 exactly
    const int l = threadIdx.x & 31;
    float acc = __half2float(x16[((size_t)g << 5) + l]);   // self-loop, ew=1
    int s = start[g], t = start[g + 1];
    int i = s;
    for (; i + 4 <= t; i += 4) {
        int2 p0 = packed[i], p1 = packed[i + 1], p2 = packed[i + 2], p3 = packed[i + 3];
        float v0 = __half2float(x16[((size_t)p0.x << 5) + l]);
        float v1 = __half2float(x16[((size_t)p1.x << 5) + l]);
        float v2 = __half2float(x16[((size_t)p2.x << 5) + l]);
        float v3 = __half2float(x16[((size_t)p3.x << 5) + l]);
        acc += __int_as_float(p0.y) * v0 + __int_as_float(p1.y) * v1
             + __int_as_float(p2.y) * v2 + __int_as_float(p3.y) * v3;
    }
    for (; i < t; ++i) {
        int2 p = packed[i];
        acc += __int_as_float(p.y) * __half2float(x16[((size_t)p.x << 5) + l]);
    }
    aggx[((size_t)g << 5) + l] = dinv[g] * acc;
}

// ---------------- gemmB: h1 = relu(aggx @ W1 + b1)   [N,26(pad32)]x[26,128] ----------------

__global__ __launch_bounds__(256) void gemmB_kernel(const float* __restrict__ aggx,
                                                    const float* __restrict__ W1,
                                                    const float* __restrict__ b1,
                                                    float* __restrict__ h1) {
    __shared__ float axs[64][32];
    const int tid = threadIdx.x;
    const int nb = blockIdx.x * 64;
    for (int t = tid; t < 64 * 32 / 4; t += 256) {
        int node = nb + (t >> 3);
        reinterpret_cast<float4*>(axs)[t] =
            (node < N_NODES)
                ? reinterpret_cast<const float4*>(aggx)[((size_t)node << 3) + (t & 7)]
                : make_float4(0.f, 0.f, 0.f, 0.f);
    }
    const int c  = tid & 127;
    const int nr = tid >> 7;
    float w[N_CLASS];
#pragma unroll
    for (int k = 0; k < N_CLASS; ++k) w[k] = W1[k * HIDDEN + c];
    const float bias = b1[c];
    __syncthreads();
    for (int tt = 0; tt < 32; ++tt) {
        int n = nr + 2 * tt;
        int node = nb + n;
        if (node < N_NODES) {
            float acc = bias;
#pragma unroll
            for (int k = 0; k < N_CLASS; ++k) acc += axs[n][k] * w[k];
            h1[(size_t)node * HIDDEN + c] = fmaxf(acc, 0.0f);
        }
    }
}

// ---------------- gemmC: p16 = fp16(dinv * (h1 @ W2))   [N,128]x[128,128] ----------------

#define CB_NODES 128
__global__ __launch_bounds__(512) void gemmC_kernel(const float* __restrict__ h1,
                                                    const float* __restrict__ W2,
                                                    const float* __restrict__ dinv,
                                                    __half* __restrict__ p16) {
    __shared__ float hs[CB_NODES][HIDDEN];   // 64 KB
    __shared__ float ws[HIDDEN][HIDDEN];     // 64 KB
    const int tid = threadIdx.x;
    const int nb = blockIdx.x * CB_NODES;
    for (int t = tid; t < HIDDEN * HIDDEN / 4; t += 512)
        reinterpret_cast<float4*>(ws)[t] = reinterpret_cast<const float4*>(W2)[t];
    for (int t = tid; t < CB_NODES * HIDDEN / 4; t += 512) {
        int node = nb + t / (HIDDEN / 4);
        reinterpret_cast<float4*>(hs)[t] =
            (node < N_NODES)
                ? reinterpret_cast<const float4*>(h1)[(size_t)node * (HIDDEN / 4) + (t & (HIDDEN / 4 - 1))]
                : make_float4(0.f, 0.f, 0.f, 0.f);
    }
    __syncthreads();
    const int c4 = (tid & 31) * 4;
    const int n0 = (tid >> 5) * 8;
    float acc[8][4] = {};
    for (int k4 = 0; k4 < HIDDEN; k4 += 4) {
        float4 wv[4];
#pragma unroll
        for (int kk = 0; kk < 4; ++kk)
            wv[kk] = *reinterpret_cast<const float4*>(&ws[k4 + kk][c4]);
#pragma unroll
        for (int i = 0; i < 8; ++i) {
            float4 hv = *reinterpret_cast<const float4*>(&hs[n0 + i][k4]);
            acc[i][0] += hv.x * wv[0].x + hv.y * wv[1].x + hv.z * wv[2].x + hv.w * wv[3].x;
            acc[i][1] += hv.x * wv[0].y + hv.y * wv[1].y + hv.z * wv[2].y + hv.w * wv[3].y;
            acc[i][2] += hv.x * wv[0].z + hv.y * wv[1].z + hv.z * wv[2].z + hv.w * wv[3].z;
            acc[i][3] += hv.x * wv[0].w + hv.y * wv[1].w + hv.z * wv[2].w + hv.w * wv[3].w;
        }
    }
#pragma unroll
    for (int i = 0; i < 8; ++i) {
        int node = nb + n0 + i;
        if (node < N_NODES) {
            float d = dinv[node];
            union { __half2 h2[2]; uint2 u; } pk;
            pk.h2[0] = __floats2half2_rn(d * acc[i][0], d * acc[i][1]);
            pk.h2[1] = __floats2half2_rn(d * acc[i][2], d * acc[i][3]);
            *reinterpret_cast<uint2*>(&p16[(size_t)node * HIDDEN + c4]) = pk.u;
        }
    }
}

// ---------------- aggfc: out = relu(dinv*(p16[g] + sum ew*p16[src]) + b2) @ Wfc + bfc ----------------

__global__ __launch_bounds__(256) void aggfc_kernel(const __half* __restrict__ p16,
                                                    const int* __restrict__ start,
                                                    const int2* __restrict__ packed,
                                                    const float* __restrict__ dinv,
                                                    const float* __restrict__ b2,
                                                    const float* __restrict__ Wfc,
                                                    const float* __restrict__ bfc,
                                                    float* __restrict__ out) {
    __shared__ float wfs[HIDDEN * N_CLASS];
    __shared__ float bfs[N_CLASS];
    __shared__ float zs[8][HIDDEN];
    const int tid = threadIdx.x;
    for (int t = tid; t < HIDDEN * N_CLASS; t += 256) wfs[t] = Wfc[t];
    if (tid < N_CLASS) bfs[tid] = bfc[tid];
    __syncthreads();

    const int grp = tid >> 5;
    const int l   = tid & 31;
    const int g   = blockIdx.x * 8 + grp;   // 12500*8 == 100000 exactly
    const int f   = l * 4;
    const h4v* P  = reinterpret_cast<const h4v*>(p16);

    h4v vs = P[((size_t)g << 5) + l];       // self-loop, ew=1
    float2 s01 = __half22float2(vs.a), s23 = __half22float2(vs.b);
    float4 acc = make_float4(s01.x, s01.y, s23.x, s23.y);

    int s = start[g], t = start[g + 1];
    int i = s;
    for (; i + 4 <= t; i += 4) {
        int2 p0 = packed[i], p1 = packed[i + 1], p2 = packed[i + 2], p3 = packed[i + 3];
        h4v v0 = P[((size_t)p0.x << 5) + l];
        h4v v1 = P[((size_t)p1.x << 5) + l];
        h4v v2 = P[((size_t)p2.x << 5) + l];
        h4v v3 = P[((size_t)p3.x << 5) + l];
        float w0 = __int_as_float(p0.y), w1 = __int_as_float(p1.y);
        float w2 = __int_as_float(p2.y), w3 = __int_as_float(p3.y);
        float2 a0 = __half22float2(v0.a), b0 = __half22float2(v0.b);
        float2 a1 = __half22float2(v1.a), b1_ = __half22float2(v1.b);
        float2 a2 = __half22float2(v2.a), b2_ = __half22float2(v2.b);
        float2 a3 = __half22float2(v3.a), b3_ = __half22float2(v3.b);
        acc.x += w0 * a0.x + w1 * a1.x + w2 * a2.x + w3 * a3.x;
        acc.y += w0 * a0.y + w1 * a1.y + w2 * a2.y + w3 * a3.y;
        acc.z += w0 * b0.x + w1 * b1_.x + w2 * b2_.x + w3 * b3_.x;
        acc.w += w0 * b0.y + w1 * b1_.y + w2 * b2_.y + w3 * b3_.y;
    }
    for (; i < t; ++i) {
        int2 p = packed[i];
        float w = __int_as_float(p.y);
        h4v v = P[((size_t)p.x << 5) + l];
        float2 a = __half22float2(v.a), b = __half22float2(v.b);
        acc.x += w * a.x; acc.y += w * a.y; acc.z += w * b.x; acc.w += w * b.y;
    }

    float dg = dinv[g];
    float4 bz = *reinterpret_cast<const float4*>(&b2[f]);
    float4 z = make_float4(fmaxf(dg * acc.x + bz.x, 0.f), fmaxf(dg * acc.y + bz.y, 0.f),
                           fmaxf(dg * acc.z + bz.z, 0.f), fmaxf(dg * acc.w + bz.w, 0.f));
    *reinterpret_cast<float4*>(&zs[grp][f]) = z;
    if (l < N_CLASS) {
        float acc2 = bfs[l];
#pragma unroll 8
        for (int k = 0; k < HIDDEN; ++k) acc2 += zs[grp][k] * wfs[k * N_CLASS + l];
        out[(size_t)g * N_CLASS + l] = acc2;
    }
}

// ---------------- launch ----------------

extern "C" void kernel_launch(void* const* d_in, const int* in_sizes, int n_in,
                              void* d_out, int out_size, void* d_ws, size_t ws_size,
                              hipStream_t stream) {
    const float* x   = (const float*)d_in[0];
    const int*   ei  = (const int*)  d_in[1];
    const float* ew  = (const float*)d_in[2];
    const float* W1  = (const float*)d_in[3];
    const float* b1  = (const float*)d_in[4];
    const float* W2  = (const float*)d_in[5];
    const float* b2  = (const float*)d_in[6];
    const float* Wfc = (const float*)d_in[7];
    const float* bfc = (const float*)d_in[8];
    float* out = (float*)d_out;

    const int n = N_NODES, E = N_EDGES;
    const int* row = ei;
    const int* col = ei + E;

    char* ws = (char*)d_ws;
    size_t off = 0;
    auto alloc = [&](size_t bytes) -> void* {
        void* ptr = ws + off;
        off += (bytes + 255) & ~(size_t)255;
        return ptr;
    };
    int*   bukcnt  = (int*)  alloc(NBUK * 4);
    int*   bukbase = (int*)  alloc(NBUK * 4);
    float* dinv    = (float*)alloc((size_t)n * 4);
    int*   start   = (int*)  alloc((size_t)(n + 1) * 4);
    int2*  packed  = (int2*) alloc((size_t)E * 8);
    __half* x16    = (__half*)alloc((size_t)n * 32 * 2);
    float* aggx    = (float*)alloc((size_t)n * 32 * 4);
    float* h1      = (float*)alloc((size_t)n * HIDDEN * 4);
    __half* p16    = (__half*)alloc((size_t)n * HIDDEN * 2);
    int2*  stage   = (int2*)h1;   // alias: stage (16 MB) dead before gemmB writes h1

    hipMemsetAsync(bukcnt, 0, NBUK * 4, stream);
    bucket_kernel<<<PB_BLOCKS, 1024, 0, stream>>>(row, col, ew, bukcnt, stage);
    bukscan_kernel<<<1, 256, 0, stream>>>(bukcnt, bukbase, start);
    csr_kernel<<<NBUK, 1024, 0, stream>>>(stage, bukcnt, bukbase, x, start, dinv, x16, packed);

    // layer 1
    gather26_kernel<<<(n + 7) / 8, 256, 0, stream>>>(x16, start, packed, dinv, aggx);
    gemmB_kernel<<<(n + 63) / 64, 256, 0, stream>>>(aggx, W1, b1, h1);

    // layer 2 + FC
    gemmC_kernel<<<(n + CB_NODES - 1) / CB_NODES, 512, 0, stream>>>(h1, W2, dinv, p16);
    aggfc_kernel<<<(n + 7) / 8, 256, 0, stream>>>(p16, start, packed, dinv, b2, Wfc, bfc, out);
}

// Round 6
// 228.789 us; speedup vs baseline: 27.7919x; 1.2308x over previous
//
#include <hip/hip_runtime.h>
#include <hip/hip_fp16.h>

#define N_NODES 100000
#define N_EDGES 1600000
#define HIDDEN  128
#define N_CLASS 26

#define BUK_SHIFT 9
#define BUK_DSTS  512
#define NBUK      196            // ceil(100000/512)
#define BUK_CAP   10240          // avg 8163, wide headroom
#define PB_EDGES  8192
#define PB_BLOCKS ((N_EDGES + PB_EDGES - 1) / PB_EDGES)   // 196

typedef _Float16 f16x2 __attribute__((ext_vector_type(2)));

__device__ __forceinline__ float fdot2(__half2 a, __half2 b, float c) {
#if __has_builtin(__builtin_amdgcn_fdot2)
    union { __half2 h; f16x2 v; } ua, ub;
    ua.h = a; ub.h = b;
    return __builtin_amdgcn_fdot2(ua.v, ub.v, c, false);
#else
    float2 fa = __half22float2(a), fb = __half22float2(b);
    return c + fa.x * fb.x + fa.y * fb.y;
#endif
}

union U4 { uint4 u; __half2 h[4]; };
union U2 { uint2 u; __half2 h[2]; };
union UW { int i; __half2 h; };

// ---------------- pass B: bucket edges by dst>>9 with coalesced run writes ----------------

__global__ __launch_bounds__(1024) void bucket_kernel(const int* __restrict__ row,
                                                      const int* __restrict__ col,
                                                      const float* __restrict__ ew,
                                                      int* __restrict__ bukcnt,
                                                      int2* __restrict__ stage) {
    __shared__ int2 outst[PB_EDGES];            // 64 KB
    __shared__ unsigned short bukof[PB_EDGES];  // 16 KB
    __shared__ int cnt[NBUK], ofs[NBUK], cur[NBUK], gt[NBUK];
    __shared__ int sc[256];
    const int tid = threadIdx.x;
    const int e0 = blockIdx.x * PB_EDGES;
    const int nvalid = min(PB_EDGES, N_EDGES - e0);

    for (int b = tid; b < NBUK; b += 1024) { cnt[b] = 0; cur[b] = 0; }
    __syncthreads();

    int mykey[8]; float myw[8]; int mybuk[8];
#pragma unroll
    for (int i = 0; i < 8; ++i) {
        int idx = tid + i * 1024;                 // coalesced
        mybuk[i] = -1;
        if (idx < nvalid) {
            int e = e0 + idx;
            int d = col[e], r = row[e];
            int buk = d >> BUK_SHIFT;
            mykey[i] = ((d & (BUK_DSTS - 1)) << 17) | r;
            myw[i] = ew[e];
            mybuk[i] = buk;
            atomicAdd(&cnt[buk], 1);
        }
    }
    __syncthreads();

    // exclusive scan cnt[196] -> ofs
    {
        int c = (tid < NBUK) ? cnt[tid] : 0;
        if (tid < 256) sc[tid] = c;
        __syncthreads();
        for (int o = 1; o < 256; o <<= 1) {
            int v = 0;
            if (tid < 256 && tid >= o) v = sc[tid - o];
            __syncthreads();
            if (tid < 256) sc[tid] += v;
            __syncthreads();
        }
        if (tid < NBUK) ofs[tid] = sc[tid] - c;
        __syncthreads();
    }

#pragma unroll
    for (int i = 0; i < 8; ++i) {
        if (mybuk[i] >= 0) {
            int s = ofs[mybuk[i]] + atomicAdd(&cur[mybuk[i]], 1);
            outst[s] = make_int2(mykey[i], __float_as_int(myw[i]));
            bukof[s] = (unsigned short)mybuk[i];
        }
    }
    __syncthreads();

    if (tid < NBUK) {
        int c = cnt[tid];
        int gb = (c > 0) ? atomicAdd(&bukcnt[tid], c) : 0;
        gt[tid] = tid * BUK_CAP + gb;
    }
    __syncthreads();

    for (int i = tid; i < nvalid; i += 1024) {
        int b = bukof[i];
        stage[(size_t)gt[b] + (i - ofs[b])] = outst[i];
    }
}

// ---------------- scan bucket totals -> compact CSR bases ----------------

__global__ void bukscan_kernel(const int* __restrict__ bukcnt, int* __restrict__ bukbase,
                               int* __restrict__ start) {
    __shared__ int s[256];
    int tid = threadIdx.x;
    int c = (tid < NBUK) ? bukcnt[tid] : 0;
    s[tid] = c;
    __syncthreads();
    for (int o = 1; o < 256; o <<= 1) {
        int v = (tid >= o) ? s[tid - o] : 0;
        __syncthreads();
        s[tid] += v;
        __syncthreads();
    }
    if (tid < NBUK) bukbase[tid] = s[tid] - c;
    if (tid == 0) start[N_NODES] = N_EDGES;
}

// ---------------- pass C: per-bucket CSR + dinv + x16 (w packed as half2) ----------------

__global__ __launch_bounds__(1024) void csr_kernel(const int2* __restrict__ stage,
                                                   const int* __restrict__ bukcnt,
                                                   const int* __restrict__ bukbase,
                                                   const float* __restrict__ x,
                                                   int* __restrict__ start,
                                                   float* __restrict__ dinv,
                                                   __half* __restrict__ x16,
                                                   int2* __restrict__ packed) {
    __shared__ unsigned int cnt5[BUK_DSTS];
    __shared__ int ofs5[BUK_DSTS];
    __shared__ unsigned int cur5[BUK_DSTS];
    __shared__ float deg5[BUK_DSTS];
    __shared__ float dv5[BUK_DSTS];
    __shared__ int sc[BUK_DSTS];
    const int tid = threadIdx.x;
    const int b = blockIdx.x;
    const int total = bukcnt[b];
    const int base = bukbase[b];
    const int2* st = stage + (size_t)b * BUK_CAP;

    for (int j = tid; j < BUK_DSTS; j += 1024) { cnt5[j] = 0; cur5[j] = 0; deg5[j] = 0.0f; }
    __syncthreads();

    for (int i = tid; i < total; i += 1024) {
        int2 en = st[i];
        int dl = en.x >> 17;
        atomicAdd(&cnt5[dl], 1u);
        atomicAdd(&deg5[dl], __int_as_float(en.y));
    }
    __syncthreads();

    {
        int c = (tid < BUK_DSTS) ? (int)cnt5[tid] : 0;
        if (tid < BUK_DSTS) sc[tid] = c;
        __syncthreads();
        for (int o = 1; o < BUK_DSTS; o <<= 1) {
            int v = 0;
            if (tid < BUK_DSTS && tid >= o) v = sc[tid - o];
            __syncthreads();
            if (tid < BUK_DSTS) sc[tid] += v;
            __syncthreads();
        }
        if (tid < BUK_DSTS) ofs5[tid] = sc[tid] - c;
        __syncthreads();
    }

    if (tid < BUK_DSTS) {
        int d = (b << BUK_SHIFT) + tid;
        if (d < N_NODES) {
            float dv = rsqrtf(deg5[tid] + 1.0f);    // +1 self-loop
            dv5[tid] = dv;
            dinv[d] = dv;
            start[d] = base + ofs5[tid];
        }
    }
    __syncthreads();

    for (int t = tid; t < BUK_DSTS * 32; t += 1024) {
        int j = t >> 5, l = t & 31;
        int d = (b << BUK_SHIFT) + j;
        if (d < N_NODES) {
            float v = (l < N_CLASS) ? x[(size_t)d * N_CLASS + l] * dv5[j] : 0.0f;
            x16[((size_t)d << 5) + l] = __float2half(v);
        }
    }

    for (int i = tid; i < total; i += 1024) {
        int2 en = st[i];
        int dl = en.x >> 17;
        int src = en.x & 0x1FFFF;
        unsigned int r = atomicAdd(&cur5[dl], 1u);
        unsigned int hw = __half_as_ushort(__float2half(__int_as_float(en.y)));
        packed[(size_t)base + ofs5[dl] + (int)r] = make_int2(src, (int)(hw | (hw << 16)));
    }
}

// ---------------- gather26: aggx[g] = dinv[g]*(x16[g] + sum ew*x16[src]) ----------------
// 8 lanes/node (dwordx2 = 4 halves), 32 nodes per 256-thread block, packed hfma2.

__global__ __launch_bounds__(256) void gather26_kernel(const __half* __restrict__ x16,
                                                       const int* __restrict__ start,
                                                       const int2* __restrict__ packed,
                                                       const float* __restrict__ dinv,
                                                       float* __restrict__ aggx) {
    const int g = blockIdx.x * 32 + (threadIdx.x >> 3);   // 3125*32 == 100000
    const int l = threadIdx.x & 7;
    const uint2* X = reinterpret_cast<const uint2*>(x16); // row = 8 uint2
    U2 sv; sv.u = X[((size_t)g << 3) + l];
    __half2 acc0 = sv.h[0], acc1 = sv.h[1];               // self-loop, ew=1
    int s = start[g], t = start[g + 1];
    int i = s;
    for (; i + 4 <= t; i += 4) {
        int2 p0 = packed[i], p1 = packed[i + 1], p2 = packed[i + 2], p3 = packed[i + 3];
        U2 v0, v1, v2, v3;
        v0.u = X[((size_t)p0.x << 3) + l];
        v1.u = X[((size_t)p1.x << 3) + l];
        v2.u = X[((size_t)p2.x << 3) + l];
        v3.u = X[((size_t)p3.x << 3) + l];
        UW w0, w1, w2, w3;
        w0.i = p0.y; w1.i = p1.y; w2.i = p2.y; w3.i = p3.y;
        acc0 = __hfma2(w0.h, v0.h[0], acc0); acc1 = __hfma2(w0.h, v0.h[1], acc1);
        acc0 = __hfma2(w1.h, v1.h[0], acc0); acc1 = __hfma2(w1.h, v1.h[1], acc1);
        acc0 = __hfma2(w2.h, v2.h[0], acc0); acc1 = __hfma2(w2.h, v2.h[1], acc1);
        acc0 = __hfma2(w3.h, v3.h[0], acc0); acc1 = __hfma2(w3.h, v3.h[1], acc1);
    }
    for (; i < t; ++i) {
        int2 p = packed[i];
        U2 v; v.u = X[((size_t)p.x << 3) + l];
        UW w; w.i = p.y;
        acc0 = __hfma2(w.h, v.h[0], acc0); acc1 = __hfma2(w.h, v.h[1], acc1);
    }
    float dg = dinv[g];
    float2 a = __half22float2(acc0), b = __half22float2(acc1);
    float4 o = make_float4(dg * a.x, dg * a.y, dg * b.x, dg * b.y);
    reinterpret_cast<float4*>(aggx)[((size_t)g << 3) + l] = o;
}

// ---------------- gemmB: h16 = fp16(relu(aggx @ W1 + b1))   [N,26(pad32)]x[26,128] ----------------

__global__ __launch_bounds__(256) void gemmB_kernel(const float* __restrict__ aggx,
                                                    const float* __restrict__ W1,
                                                    const float* __restrict__ b1,
                                                    __half* __restrict__ h16) {
    __shared__ float axs[64][32];
    const int tid = threadIdx.x;
    const int nb = blockIdx.x * 64;
    for (int t = tid; t < 64 * 32 / 4; t += 256) {
        int node = nb + (t >> 3);
        reinterpret_cast<float4*>(axs)[t] =
            (node < N_NODES)
                ? reinterpret_cast<const float4*>(aggx)[((size_t)node << 3) + (t & 7)]
                : make_float4(0.f, 0.f, 0.f, 0.f);
    }
    const int c  = tid & 127;
    const int nr = tid >> 7;
    float w[N_CLASS];
#pragma unroll
    for (int k = 0; k < N_CLASS; ++k) w[k] = W1[k * HIDDEN + c];
    const float bias = b1[c];
    __syncthreads();
    for (int tt = 0; tt < 32; ++tt) {
        int n = nr + 2 * tt;
        int node = nb + n;
        if (node < N_NODES) {
            float acc = bias;
#pragma unroll
            for (int k = 0; k < N_CLASS; ++k) acc += axs[n][k] * w[k];
            h16[(size_t)node * HIDDEN + c] = __float2half(fmaxf(acc, 0.0f));
        }
    }
}

// ---------------- gemmC: p16 = fp16(dinv * (h16 @ W2)) via fdot2 ----------------

#define CB_NODES 128
__global__ __launch_bounds__(512) void gemmC_kernel(const __half* __restrict__ h16,
                                                    const float* __restrict__ W2,
                                                    const float* __restrict__ dinv,
                                                    __half* __restrict__ p16) {
    __shared__ __half2 hs2[CB_NODES][HIDDEN / 2];   // 32 KB  [node][k2]
    __shared__ __half2 ws2[HIDDEN / 2][HIDDEN];     // 32 KB  [k2][c]
    const int tid = threadIdx.x;
    const int nb = blockIdx.x * CB_NODES;
    for (int t = tid; t < HIDDEN / 2 * HIDDEN; t += 512) {
        int k2 = t >> 7, c = t & 127;
        ws2[k2][c] = __floats2half2_rn(W2[(2 * k2) * HIDDEN + c], W2[(2 * k2 + 1) * HIDDEN + c]);
    }
    for (int t = tid; t < CB_NODES * 16; t += 512) {   // 16 uint4 per row
        int node = nb + (t >> 4);
        reinterpret_cast<uint4*>(hs2)[t] =
            (node < N_NODES)
                ? reinterpret_cast<const uint4*>(h16)[(size_t)node * 16 + (t & 15)]
                : make_uint4(0u, 0u, 0u, 0u);
    }
    __syncthreads();
    const int c4 = (tid & 31) * 4;
    const int n0 = (tid >> 5) * 8;
    float acc[8][4] = {};
    for (int k2 = 0; k2 < HIDDEN / 2; k2 += 2) {
        U4 wa, wb;
        wa.u = *reinterpret_cast<const uint4*>(&ws2[k2][c4]);
        wb.u = *reinterpret_cast<const uint4*>(&ws2[k2 + 1][c4]);
#pragma unroll
        for (int i = 0; i < 8; ++i) {
            U2 hv; hv.u = *reinterpret_cast<const uint2*>(&hs2[n0 + i][k2]);
#pragma unroll
            for (int q = 0; q < 4; ++q) {
                acc[i][q] = fdot2(hv.h[0], wa.h[q], acc[i][q]);
                acc[i][q] = fdot2(hv.h[1], wb.h[q], acc[i][q]);
            }
        }
    }
#pragma unroll
    for (int i = 0; i < 8; ++i) {
        int node = nb + n0 + i;
        if (node < N_NODES) {
            float d = dinv[node];
            union { __half2 h2[2]; uint2 u; } pk;
            pk.h2[0] = __floats2half2_rn(d * acc[i][0], d * acc[i][1]);
            pk.h2[1] = __floats2half2_rn(d * acc[i][2], d * acc[i][3]);
            *reinterpret_cast<uint2*>(&p16[(size_t)node * HIDDEN + c4]) = pk.u;
        }
    }
}

// ---------------- aggfc: out = relu(dinv*(p16[g] + sum ew*p16[src]) + b2) @ Wfc + bfc ----------------
// 16 lanes/node (dwordx4 = 8 halves), 16 nodes per 256-thread block, hfma2 + fdot2 FC.

__global__ __launch_bounds__(256) void aggfc_kernel(const __half* __restrict__ p16,
                                                    const int* __restrict__ start,
                                                    const int2* __restrict__ packed,
                                                    const float* __restrict__ dinv,
                                                    const float* __restrict__ b2,
                                                    const float* __restrict__ Wfc,
                                                    const float* __restrict__ bfc,
                                                    float* __restrict__ out) {
    __shared__ __half2 wf2[HIDDEN / 2][N_CLASS];   // 6656 B  [k2][j]
    __shared__ float bfs[N_CLASS];
    __shared__ __half2 zs2[16][HIDDEN / 2];        // 4 KB
    const int tid = threadIdx.x;
    for (int t = tid; t < HIDDEN / 2 * N_CLASS; t += 256) {
        int k2 = t / N_CLASS, j = t % N_CLASS;
        wf2[k2][j] = __floats2half2_rn(Wfc[(2 * k2) * N_CLASS + j], Wfc[(2 * k2 + 1) * N_CLASS + j]);
    }
    if (tid < N_CLASS) bfs[tid] = bfc[tid];
    __syncthreads();

    const int grp = tid >> 4;
    const int l   = tid & 15;
    const int g   = blockIdx.x * 16 + grp;          // 6250*16 == 100000
    const uint4* P = reinterpret_cast<const uint4*>(p16);   // row = 16 uint4

    U4 sv; sv.u = P[((size_t)g << 4) + l];          // self-loop, ew=1
    __half2 acc0 = sv.h[0], acc1 = sv.h[1], acc2 = sv.h[2], acc3 = sv.h[3];

    int s = start[g], t = start[g + 1];
    int i = s;
    for (; i + 2 <= t; i += 2) {
        int2 pa = packed[i], pb = packed[i + 1];
        U4 va, vb;
        va.u = P[((size_t)pa.x << 4) + l];
        vb.u = P[((size_t)pb.x << 4) + l];
        UW wa, wb; wa.i = pa.y; wb.i = pb.y;
        acc0 = __hfma2(wa.h, va.h[0], acc0); acc1 = __hfma2(wa.h, va.h[1], acc1);
        acc2 = __hfma2(wa.h, va.h[2], acc2); acc3 = __hfma2(wa.h, va.h[3], acc3);
        acc0 = __hfma2(wb.h, vb.h[0], acc0); acc1 = __hfma2(wb.h, vb.h[1], acc1);
        acc2 = __hfma2(wb.h, vb.h[2], acc2); acc3 = __hfma2(wb.h, vb.h[3], acc3);
    }
    for (; i < t; ++i) {
        int2 p = packed[i];
        U4 v; v.u = P[((size_t)p.x << 4) + l];
        UW w; w.i = p.y;
        acc0 = __hfma2(w.h, v.h[0], acc0); acc1 = __hfma2(w.h, v.h[1], acc1);
        acc2 = __hfma2(w.h, v.h[2], acc2); acc3 = __hfma2(w.h, v.h[3], acc3);
    }

    const float dg = dinv[g];
    const int f = l * 8;
    float4 ba = *reinterpret_cast<const float4*>(&b2[f]);
    float4 bb = *reinterpret_cast<const float4*>(&b2[f + 4]);
    float2 f0 = __half22float2(acc0), f1 = __half22float2(acc1);
    float2 f2 = __half22float2(acc2), f3 = __half22float2(acc3);
    zs2[grp][l * 4 + 0] = __floats2half2_rn(fmaxf(dg * f0.x + ba.x, 0.f), fmaxf(dg * f0.y + ba.y, 0.f));
    zs2[grp][l * 4 + 1] = __floats2half2_rn(fmaxf(dg * f1.x + ba.z, 0.f), fmaxf(dg * f1.y + ba.w, 0.f));
    zs2[grp][l * 4 + 2] = __floats2half2_rn(fmaxf(dg * f2.x + bb.x, 0.f), fmaxf(dg * f2.y + bb.y, 0.f));
    zs2[grp][l * 4 + 3] = __floats2half2_rn(fmaxf(dg * f3.x + bb.z, 0.f), fmaxf(dg * f3.y + bb.w, 0.f));
    // 16-lane group lives in one wave: lockstep, no barrier needed for zs2 reuse.
#pragma unroll
    for (int jj = l; jj < N_CLASS; jj += 16) {
        float accf = bfs[jj];
#pragma unroll 16
        for (int k2 = 0; k2 < HIDDEN / 2; ++k2)
            accf = fdot2(zs2[grp][k2], wf2[k2][jj], accf);
        out[(size_t)g * N_CLASS + jj] = accf;
    }
}

// ---------------- launch ----------------

extern "C" void kernel_launch(void* const* d_in, const int* in_sizes, int n_in,
                              void* d_out, int out_size, void* d_ws, size_t ws_size,
                              hipStream_t stream) {
    const float* x   = (const float*)d_in[0];
    const int*   ei  = (const int*)  d_in[1];
    const float* ew  = (const float*)d_in[2];
    const float* W1  = (const float*)d_in[3];
    const float* b1  = (const float*)d_in[4];
    const float* W2  = (const float*)d_in[5];
    const float* b2  = (const float*)d_in[6];
    const float* Wfc = (const float*)d_in[7];
    const float* bfc = (const float*)d_in[8];
    float* out = (float*)d_out;

    const int n = N_NODES, E = N_EDGES;
    const int* row = ei;
    const int* col = ei + E;

    char* ws = (char*)d_ws;
    size_t off = 0;
    auto alloc = [&](size_t bytes) -> void* {
        void* ptr = ws + off;
        off += (bytes + 255) & ~(size_t)255;
        return ptr;
    };
    int*   bukcnt  = (int*)  alloc(NBUK * 4);
    int*   bukbase = (int*)  alloc(NBUK * 4);
    float* dinv    = (float*)alloc((size_t)n * 4);
    int*   start   = (int*)  alloc((size_t)(n + 1) * 4);
    int2*  packed  = (int2*) alloc((size_t)E * 8);
    __half* x16    = (__half*)alloc((size_t)n * 32 * 2);
    float* aggx    = (float*)alloc((size_t)n * 32 * 4);
    __half* h16    = (__half*)alloc((size_t)n * HIDDEN * 2 < (size_t)NBUK * BUK_CAP * 8
                                        ? (size_t)NBUK * BUK_CAP * 8
                                        : (size_t)n * HIDDEN * 2);
    __half* p16    = (__half*)alloc((size_t)n * HIDDEN * 2);
    int2*  stage   = (int2*)h16;   // alias: stage (16 MB) dead before gemmB writes h16

    hipMemsetAsync(bukcnt, 0, NBUK * 4, stream);
    bucket_kernel<<<PB_BLOCKS, 1024, 0, stream>>>(row, col, ew, bukcnt, stage);
    bukscan_kernel<<<1, 256, 0, stream>>>(bukcnt, bukbase, start);
    csr_kernel<<<NBUK, 1024, 0, stream>>>(stage, bukcnt, bukbase, x, start, dinv, x16, packed);

    // layer 1
    gather26_kernel<<<(n + 31) / 32, 256, 0, stream>>>(x16, start, packed, dinv, aggx);
    gemmB_kernel<<<(n + 63) / 64, 256, 0, stream>>>(aggx, W1, b1, h16);

    // layer 2 + FC
    gemmC_kernel<<<(n + CB_NODES - 1) / CB_NODES, 512, 0, stream>>>(h16, W2, dinv, p16);
    aggfc_kernel<<<(n + 15) / 16, 256, 0, stream>>>(p16, start, packed, dinv, b2, Wfc, bfc, out);
}

// Round 7
// 221.174 us; speedup vs baseline: 28.7487x; 1.0344x over previous
//
#include <hip/hip_runtime.h>
#include <hip/hip_fp16.h>

#define N_NODES 100000
#define N_EDGES 1600000
#define HIDDEN  128
#define N_CLASS 26

#define BUK_SHIFT 9
#define BUK_DSTS  512
#define NBUK      196            // ceil(100000/512)
#define BUK_CAP   10240          // avg 8163, wide headroom
#define PB_EDGES  8192
#define PB_BLOCKS ((N_EDGES + PB_EDGES - 1) / PB_EDGES)   // 196

typedef _Float16 f16x2 __attribute__((ext_vector_type(2)));

__device__ __forceinline__ float fdot2(__half2 a, __half2 b, float c) {
#if __has_builtin(__builtin_amdgcn_fdot2)
    union { __half2 h; f16x2 v; } ua, ub;
    ua.h = a; ub.h = b;
    return __builtin_amdgcn_fdot2(ua.v, ub.v, c, false);
#else
    float2 fa = __half22float2(a), fb = __half22float2(b);
    return c + fa.x * fb.x + fa.y * fb.y;
#endif
}

union U4 { uint4 u; __half2 h[4]; };
union U2 { uint2 u; __half2 h[2]; };
union UW { int i; __half2 h; };

// ---------------- pass B: bucket edges by dst>>9 with coalesced run writes ----------------

__global__ __launch_bounds__(1024) void bucket_kernel(const int* __restrict__ row,
                                                      const int* __restrict__ col,
                                                      const float* __restrict__ ew,
                                                      int* __restrict__ bukcnt,
                                                      int2* __restrict__ stage) {
    __shared__ int2 outst[PB_EDGES];            // 64 KB
    __shared__ unsigned short bukof[PB_EDGES];  // 16 KB
    __shared__ int cnt[NBUK], ofs[NBUK], cur[NBUK], gt[NBUK];
    __shared__ int sc[256];
    const int tid = threadIdx.x;
    const int e0 = blockIdx.x * PB_EDGES;
    const int nvalid = min(PB_EDGES, N_EDGES - e0);

    for (int b = tid; b < NBUK; b += 1024) { cnt[b] = 0; cur[b] = 0; }
    __syncthreads();

    int mykey[8]; float myw[8]; int mybuk[8];
#pragma unroll
    for (int i = 0; i < 8; ++i) {
        int idx = tid + i * 1024;                 // coalesced
        mybuk[i] = -1;
        if (idx < nvalid) {
            int e = e0 + idx;
            int d = col[e], r = row[e];
            int buk = d >> BUK_SHIFT;
            mykey[i] = ((d & (BUK_DSTS - 1)) << 17) | r;
            myw[i] = ew[e];
            mybuk[i] = buk;
            atomicAdd(&cnt[buk], 1);
        }
    }
    __syncthreads();

    // exclusive scan cnt[196] -> ofs
    {
        int c = (tid < NBUK) ? cnt[tid] : 0;
        if (tid < 256) sc[tid] = c;
        __syncthreads();
        for (int o = 1; o < 256; o <<= 1) {
            int v = 0;
            if (tid < 256 && tid >= o) v = sc[tid - o];
            __syncthreads();
            if (tid < 256) sc[tid] += v;
            __syncthreads();
        }
        if (tid < NBUK) ofs[tid] = sc[tid] - c;
        __syncthreads();
    }

#pragma unroll
    for (int i = 0; i < 8; ++i) {
        if (mybuk[i] >= 0) {
            int s = ofs[mybuk[i]] + atomicAdd(&cur[mybuk[i]], 1);
            outst[s] = make_int2(mykey[i], __float_as_int(myw[i]));
            bukof[s] = (unsigned short)mybuk[i];
        }
    }
    __syncthreads();

    if (tid < NBUK) {
        int c = cnt[tid];
        int gb = (c > 0) ? atomicAdd(&bukcnt[tid], c) : 0;
        gt[tid] = tid * BUK_CAP + gb;
    }
    __syncthreads();

    for (int i = tid; i < nvalid; i += 1024) {
        int b = bukof[i];
        stage[(size_t)gt[b] + (i - ofs[b])] = outst[i];
    }
}

// ---------------- scan bucket totals -> compact CSR bases ----------------

__global__ void bukscan_kernel(const int* __restrict__ bukcnt, int* __restrict__ bukbase,
                               int* __restrict__ start) {
    __shared__ int s[256];
    int tid = threadIdx.x;
    int c = (tid < NBUK) ? bukcnt[tid] : 0;
    s[tid] = c;
    __syncthreads();
    for (int o = 1; o < 256; o <<= 1) {
        int v = (tid >= o) ? s[tid - o] : 0;
        __syncthreads();
        s[tid] += v;
        __syncthreads();
    }
    if (tid < NBUK) bukbase[tid] = s[tid] - c;
    if (tid == 0) start[N_NODES] = N_EDGES;
}

// ---------------- pass C: per-bucket CSR + dinv + x16 + degree-sorted perm ----------------

__global__ __launch_bounds__(1024) void csr_kernel(const int2* __restrict__ stage,
                                                   const int* __restrict__ bukcnt,
                                                   const int* __restrict__ bukbase,
                                                   const float* __restrict__ x,
                                                   int* __restrict__ start,
                                                   float* __restrict__ dinv,
                                                   __half* __restrict__ x16,
                                                   int2* __restrict__ packed,
                                                   int* __restrict__ perm) {
    __shared__ unsigned int cnt5[BUK_DSTS];
    __shared__ int ofs5[BUK_DSTS];
    __shared__ unsigned int cur5[BUK_DSTS];
    __shared__ float deg5[BUK_DSTS];
    __shared__ float dv5[BUK_DSTS];
    __shared__ int sc[BUK_DSTS];
    __shared__ int dhist[128];
    __shared__ int dcur[128];
    const int tid = threadIdx.x;
    const int b = blockIdx.x;
    const int total = bukcnt[b];
    const int base = bukbase[b];
    const int2* st = stage + (size_t)b * BUK_CAP;

    for (int j = tid; j < BUK_DSTS; j += 1024) { cnt5[j] = 0; cur5[j] = 0; deg5[j] = 0.0f; }
    if (tid < 128) { dhist[tid] = 0; dcur[tid] = 0; }
    __syncthreads();

    for (int i = tid; i < total; i += 1024) {
        int2 en = st[i];
        int dl = en.x >> 17;
        atomicAdd(&cnt5[dl], 1u);
        atomicAdd(&deg5[dl], __int_as_float(en.y));
    }
    __syncthreads();

    // exclusive scan cnt5[512] -> ofs5
    {
        int c = (tid < BUK_DSTS) ? (int)cnt5[tid] : 0;
        if (tid < BUK_DSTS) sc[tid] = c;
        __syncthreads();
        for (int o = 1; o < BUK_DSTS; o <<= 1) {
            int v = 0;
            if (tid < BUK_DSTS && tid >= o) v = sc[tid - o];
            __syncthreads();
            if (tid < BUK_DSTS) sc[tid] += v;
            __syncthreads();
        }
        if (tid < BUK_DSTS) ofs5[tid] = sc[tid] - c;
        __syncthreads();
    }

    // degree histogram for within-bucket counting sort
    int myd = -1;
    {
        int d = (b << BUK_SHIFT) + tid;
        if (tid < BUK_DSTS && d < N_NODES) {
            myd = min((int)cnt5[tid], 127);
            atomicAdd(&dhist[myd], 1);
        }
    }

    if (tid < BUK_DSTS) {
        int d = (b << BUK_SHIFT) + tid;
        if (d < N_NODES) {
            float dv = rsqrtf(deg5[tid] + 1.0f);    // +1 self-loop
            dv5[tid] = dv;
            dinv[d] = dv;
            start[d] = base + ofs5[tid];
        }
    }
    __syncthreads();

    // scan dhist[128] -> ranks; perm[bucket_base + rank] = node
    if (tid < 128) sc[tid] = dhist[tid];
    __syncthreads();
    for (int o = 1; o < 128; o <<= 1) {
        int v = 0;
        if (tid < 128 && tid >= o) v = sc[tid - o];
        __syncthreads();
        if (tid < 128) sc[tid] += v;
        __syncthreads();
    }
    if (myd >= 0) {
        int rank = sc[myd] - dhist[myd] + atomicAdd(&dcur[myd], 1);
        perm[(b << BUK_SHIFT) + rank] = (b << BUK_SHIFT) + tid;
    }

    // x16 rows (prescaled by dinv, padded to 32) for this bucket's nodes
    for (int t = tid; t < BUK_DSTS * 32; t += 1024) {
        int j = t >> 5, l = t & 31;
        int d = (b << BUK_SHIFT) + j;
        if (d < N_NODES) {
            float v = (l < N_CLASS) ? x[(size_t)d * N_CLASS + l] * dv5[j] : 0.0f;
            x16[((size_t)d << 5) + l] = __float2half(v);
        }
    }

    // scatter into compact CSR region (L2-local), w packed as half2
    for (int i = tid; i < total; i += 1024) {
        int2 en = st[i];
        int dl = en.x >> 17;
        int src = en.x & 0x1FFFF;
        unsigned int r = atomicAdd(&cur5[dl], 1u);
        unsigned int hw = __half_as_ushort(__float2half(__int_as_float(en.y)));
        packed[(size_t)base + ofs5[dl] + (int)r] = make_int2(src, (int)(hw | (hw << 16)));
    }
}

// ---------------- layer1 (fused): gather26 + gemmB ----------------
// Phase 1: 8 lanes/node gather 32 perm-ordered nodes into LDS (fp32).
// Phase 2: 256 threads GEMM 32x26 @ 26x128, bias+relu, write h16.

__global__ __launch_bounds__(256) void layer1_kernel(const __half* __restrict__ x16,
                                                     const int* __restrict__ start,
                                                     const int2* __restrict__ packed,
                                                     const float* __restrict__ dinv,
                                                     const int* __restrict__ perm,
                                                     const float* __restrict__ W1,
                                                     const float* __restrict__ b1,
                                                     __half* __restrict__ h16) {
    __shared__ float axs[32][32];
    __shared__ int gl[32];
    const int tid = threadIdx.x;
    const int nb = blockIdx.x * 32;   // 3125*32 == 100000
    {
        const int j = tid >> 3;
        const int l = tid & 7;
        const int g = perm[nb + j];
        if (l == 0) gl[j] = g;
        const uint2* X = reinterpret_cast<const uint2*>(x16); // row = 8 uint2
        U2 sv; sv.u = X[((size_t)g << 3) + l];
        __half2 acc0 = sv.h[0], acc1 = sv.h[1];               // self-loop, ew=1
        int s = start[g], t = start[g + 1];
        int i = s;
        for (; i + 4 <= t; i += 4) {
            int2 p0 = packed[i], p1 = packed[i + 1], p2 = packed[i + 2], p3 = packed[i + 3];
            U2 v0, v1, v2, v3;
            v0.u = X[((size_t)p0.x << 3) + l];
            v1.u = X[((size_t)p1.x << 3) + l];
            v2.u = X[((size_t)p2.x << 3) + l];
            v3.u = X[((size_t)p3.x << 3) + l];
            UW w0, w1, w2, w3;
            w0.i = p0.y; w1.i = p1.y; w2.i = p2.y; w3.i = p3.y;
            acc0 = __hfma2(w0.h, v0.h[0], acc0); acc1 = __hfma2(w0.h, v0.h[1], acc1);
            acc0 = __hfma2(w1.h, v1.h[0], acc0); acc1 = __hfma2(w1.h, v1.h[1], acc1);
            acc0 = __hfma2(w2.h, v2.h[0], acc0); acc1 = __hfma2(w2.h, v2.h[1], acc1);
            acc0 = __hfma2(w3.h, v3.h[0], acc0); acc1 = __hfma2(w3.h, v3.h[1], acc1);
        }
        for (; i < t; ++i) {
            int2 p = packed[i];
            U2 v; v.u = X[((size_t)p.x << 3) + l];
            UW w; w.i = p.y;
            acc0 = __hfma2(w.h, v.h[0], acc0); acc1 = __hfma2(w.h, v.h[1], acc1);
        }
        float dg = dinv[g];
        float2 a = __half22float2(acc0), bb = __half22float2(acc1);
        *reinterpret_cast<float4*>(&axs[j][l * 4]) =
            make_float4(dg * a.x, dg * a.y, dg * bb.x, dg * bb.y);
    }
    __syncthreads();
    const int c = tid & 127;
    const int half = tid >> 7;
    float w[N_CLASS];
#pragma unroll
    for (int k = 0; k < N_CLASS; ++k) w[k] = W1[k * HIDDEN + c];
    const float bias = b1[c];
#pragma unroll
    for (int tt = 0; tt < 16; ++tt) {
        int n = half + 2 * tt;
        float acc = bias;
#pragma unroll
        for (int k = 0; k < N_CLASS; ++k) acc += axs[n][k] * w[k];
        h16[(size_t)gl[n] * HIDDEN + c] = __float2half(fmaxf(acc, 0.0f));
    }
}

// ---------------- gemmC: p16 = fp16(dinv * (h16 @ W2)) via fdot2 ----------------

#define CB_NODES 128
__global__ __launch_bounds__(512) void gemmC_kernel(const __half* __restrict__ h16,
                                                    const float* __restrict__ W2,
                                                    const float* __restrict__ dinv,
                                                    __half* __restrict__ p16) {
    __shared__ __half2 hs2[CB_NODES][HIDDEN / 2];   // 32 KB  [node][k2]
    __shared__ __half2 ws2[HIDDEN / 2][HIDDEN];     // 32 KB  [k2][c]
    const int tid = threadIdx.x;
    const int nb = blockIdx.x * CB_NODES;
    for (int t = tid; t < HIDDEN / 2 * HIDDEN; t += 512) {
        int k2 = t >> 7, c = t & 127;
        ws2[k2][c] = __floats2half2_rn(W2[(2 * k2) * HIDDEN + c], W2[(2 * k2 + 1) * HIDDEN + c]);
    }
    for (int t = tid; t < CB_NODES * 16; t += 512) {   // 16 uint4 per row
        int node = nb + (t >> 4);
        reinterpret_cast<uint4*>(hs2)[t] =
            (node < N_NODES)
                ? reinterpret_cast<const uint4*>(h16)[(size_t)node * 16 + (t & 15)]
                : make_uint4(0u, 0u, 0u, 0u);
    }
    __syncthreads();
    const int c4 = (tid & 31) * 4;
    const int n0 = (tid >> 5) * 8;
    float acc[8][4] = {};
    for (int k2 = 0; k2 < HIDDEN / 2; k2 += 2) {
        U4 wa, wb;
        wa.u = *reinterpret_cast<const uint4*>(&ws2[k2][c4]);
        wb.u = *reinterpret_cast<const uint4*>(&ws2[k2 + 1][c4]);
#pragma unroll
        for (int i = 0; i < 8; ++i) {
            U2 hv; hv.u = *reinterpret_cast<const uint2*>(&hs2[n0 + i][k2]);
#pragma unroll
            for (int q = 0; q < 4; ++q) {
                acc[i][q] = fdot2(hv.h[0], wa.h[q], acc[i][q]);
                acc[i][q] = fdot2(hv.h[1], wb.h[q], acc[i][q]);
            }
        }
    }
#pragma unroll
    for (int i = 0; i < 8; ++i) {
        int node = nb + n0 + i;
        if (node < N_NODES) {
            float d = dinv[node];
            union { __half2 h2[2]; uint2 u; } pk;
            pk.h2[0] = __floats2half2_rn(d * acc[i][0], d * acc[i][1]);
            pk.h2[1] = __floats2half2_rn(d * acc[i][2], d * acc[i][3]);
            *reinterpret_cast<uint2*>(&p16[(size_t)node * HIDDEN + c4]) = pk.u;
        }
    }
}

// ---------------- aggfc: out = relu(dinv*(p16[g] + sum ew*p16[src]) + b2) @ Wfc + bfc ----------------
// 16 lanes/node, perm-ordered nodes (uniform trip counts), unroll 4, padded zs2.

__global__ __launch_bounds__(256) void aggfc_kernel(const __half* __restrict__ p16,
                                                    const int* __restrict__ start,
                                                    const int2* __restrict__ packed,
                                                    const float* __restrict__ dinv,
                                                    const int* __restrict__ perm,
                                                    const float* __restrict__ b2,
                                                    const float* __restrict__ Wfc,
                                                    const float* __restrict__ bfc,
                                                    float* __restrict__ out) {
    __shared__ __half2 wf2[HIDDEN / 2][N_CLASS];   // [k2][j]
    __shared__ float bfs[N_CLASS];
    __shared__ __half2 zs2[16][65];                // pad 65: bank = k2+grp*65 mod 32, conflict-free
    const int tid = threadIdx.x;
    for (int t = tid; t < HIDDEN / 2 * N_CLASS; t += 256) {
        int k2 = t / N_CLASS, j = t % N_CLASS;
        wf2[k2][j] = __floats2half2_rn(Wfc[(2 * k2) * N_CLASS + j], Wfc[(2 * k2 + 1) * N_CLASS + j]);
    }
    if (tid < N_CLASS) bfs[tid] = bfc[tid];
    __syncthreads();

    const int grp = tid >> 4;
    const int l   = tid & 15;
    const int g   = perm[blockIdx.x * 16 + grp];    // 6250*16 == 100000
    const uint4* P = reinterpret_cast<const uint4*>(p16);   // row = 16 uint4

    U4 sv; sv.u = P[((size_t)g << 4) + l];          // self-loop, ew=1
    __half2 acc0 = sv.h[0], acc1 = sv.h[1], acc2 = sv.h[2], acc3 = sv.h[3];

    int s = start[g], t = start[g + 1];
    int i = s;
    for (; i + 4 <= t; i += 4) {
        int2 pa = packed[i], pb = packed[i + 1], pc = packed[i + 2], pd = packed[i + 3];
        U4 va, vb, vc, vd;
        va.u = P[((size_t)pa.x << 4) + l];
        vb.u = P[((size_t)pb.x << 4) + l];
        vc.u = P[((size_t)pc.x << 4) + l];
        vd.u = P[((size_t)pd.x << 4) + l];
        UW wa, wb, wc, wd; wa.i = pa.y; wb.i = pb.y; wc.i = pc.y; wd.i = pd.y;
        acc0 = __hfma2(wa.h, va.h[0], acc0); acc1 = __hfma2(wa.h, va.h[1], acc1);
        acc2 = __hfma2(wa.h, va.h[2], acc2); acc3 = __hfma2(wa.h, va.h[3], acc3);
        acc0 = __hfma2(wb.h, vb.h[0], acc0); acc1 = __hfma2(wb.h, vb.h[1], acc1);
        acc2 = __hfma2(wb.h, vb.h[2], acc2); acc3 = __hfma2(wb.h, vb.h[3], acc3);
        acc0 = __hfma2(wc.h, vc.h[0], acc0); acc1 = __hfma2(wc.h, vc.h[1], acc1);
        acc2 = __hfma2(wc.h, vc.h[2], acc2); acc3 = __hfma2(wc.h, vc.h[3], acc3);
        acc0 = __hfma2(wd.h, vd.h[0], acc0); acc1 = __hfma2(wd.h, vd.h[1], acc1);
        acc2 = __hfma2(wd.h, vd.h[2], acc2); acc3 = __hfma2(wd.h, vd.h[3], acc3);
    }
    for (; i < t; ++i) {
        int2 p = packed[i];
        U4 v; v.u = P[((size_t)p.x << 4) + l];
        UW w; w.i = p.y;
        acc0 = __hfma2(w.h, v.h[0], acc0); acc1 = __hfma2(w.h, v.h[1], acc1);
        acc2 = __hfma2(w.h, v.h[2], acc2); acc3 = __hfma2(w.h, v.h[3], acc3);
    }

    const float dg = dinv[g];
    const int f = l * 8;
    float4 ba = *reinterpret_cast<const float4*>(&b2[f]);
    float4 bb = *reinterpret_cast<const float4*>(&b2[f + 4]);
    float2 f0 = __half22float2(acc0), f1 = __half22float2(acc1);
    float2 f2 = __half22float2(acc2), f3 = __half22float2(acc3);
    zs2[grp][l * 4 + 0] = __floats2half2_rn(fmaxf(dg * f0.x + ba.x, 0.f), fmaxf(dg * f0.y + ba.y, 0.f));
    zs2[grp][l * 4 + 1] = __floats2half2_rn(fmaxf(dg * f1.x + ba.z, 0.f), fmaxf(dg * f1.y + ba.w, 0.f));
    zs2[grp][l * 4 + 2] = __floats2half2_rn(fmaxf(dg * f2.x + bb.x, 0.f), fmaxf(dg * f2.y + bb.y, 0.f));
    zs2[grp][l * 4 + 3] = __floats2half2_rn(fmaxf(dg * f3.x + bb.z, 0.f), fmaxf(dg * f3.y + bb.w, 0.f));
    // 16-lane group lives in one wave: lockstep, no barrier needed for zs2 reuse.
#pragma unroll
    for (int jj = l; jj < N_CLASS; jj += 16) {
        float accf = bfs[jj];
#pragma unroll 16
        for (int k2 = 0; k2 < HIDDEN / 2; ++k2)
            accf = fdot2(zs2[grp][k2], wf2[k2][jj], accf);
        out[(size_t)g * N_CLASS + jj] = accf;
    }
}

// ---------------- launch ----------------

extern "C" void kernel_launch(void* const* d_in, const int* in_sizes, int n_in,
                              void* d_out, int out_size, void* d_ws, size_t ws_size,
                              hipStream_t stream) {
    const float* x   = (const float*)d_in[0];
    const int*   ei  = (const int*)  d_in[1];
    const float* ew  = (const float*)d_in[2];
    const float* W1  = (const float*)d_in[3];
    const float* b1  = (const float*)d_in[4];
    const float* W2  = (const float*)d_in[5];
    const float* b2  = (const float*)d_in[6];
    const float* Wfc = (const float*)d_in[7];
    const float* bfc = (const float*)d_in[8];
    float* out = (float*)d_out;

    const int n = N_NODES, E = N_EDGES;
    const int* row = ei;
    const int* col = ei + E;

    char* ws = (char*)d_ws;
    size_t off = 0;
    auto alloc = [&](size_t bytes) -> void* {
        void* ptr = ws + off;
        off += (bytes + 255) & ~(size_t)255;
        return ptr;
    };
    int*   bukcnt  = (int*)  alloc(NBUK * 4);
    int*   bukbase = (int*)  alloc(NBUK * 4);
    float* dinv    = (float*)alloc((size_t)n * 4);
    int*   start   = (int*)  alloc((size_t)(n + 1) * 4);
    int*   perm    = (int*)  alloc((size_t)n * 4);
    int2*  packed  = (int2*) alloc((size_t)E * 8);
    __half* x16    = (__half*)alloc((size_t)n * 32 * 2);
    __half* h16    = (__half*)alloc((size_t)n * HIDDEN * 2 < (size_t)NBUK * BUK_CAP * 8
                                        ? (size_t)NBUK * BUK_CAP * 8
                                        : (size_t)n * HIDDEN * 2);
    __half* p16    = (__half*)alloc((size_t)n * HIDDEN * 2);
    int2*  stage   = (int2*)h16;   // alias: stage (16 MB) dead before layer1 writes h16

    hipMemsetAsync(bukcnt, 0, NBUK * 4, stream);
    bucket_kernel<<<PB_BLOCKS, 1024, 0, stream>>>(row, col, ew, bukcnt, stage);
    bukscan_kernel<<<1, 256, 0, stream>>>(bukcnt, bukbase, start);
    csr_kernel<<<NBUK, 1024, 0, stream>>>(stage, bukcnt, bukbase, x, start, dinv, x16, packed, perm);

    // layer 1 (fused gather + GEMM)
    layer1_kernel<<<(n + 31) / 32, 256, 0, stream>>>(x16, start, packed, dinv, perm, W1, b1, h16);

    // layer 2 + FC
    gemmC_kernel<<<(n + CB_NODES - 1) / CB_NODES, 512, 0, stream>>>(h16, W2, dinv, p16);
    aggfc_kernel<<<(n + 15) / 16, 256, 0, stream>>>(p16, start, packed, dinv, perm, b2, Wfc, bfc, out);
}